// Round 5
// baseline (522.633 us; speedup 1.0000x reference)
//
#include <hip/hip_runtime.h>
#include <stdint.h>
#include <stddef.h>

#define NB 32
#define NN 8192
#define NH 512
#define NE 10
#define HEPS 1e-5f
#define HSLOPE 0.2f

typedef short short8 __attribute__((ext_vector_type(8)));
typedef float f32x4 __attribute__((ext_vector_type(4)));

static __device__ __forceinline__ unsigned short f2bf(float f){
  unsigned u = __float_as_uint(f);
  u += 0x7FFFu + ((u >> 16) & 1u);   // RNE
  return (unsigned short)(u >> 16);
}
static __device__ __forceinline__ float bf2f(unsigned short h){
  return __uint_as_float(((unsigned)h) << 16);
}

// ---------------------------------------------------------------------------
// Prep: W2 [E][512][256] f32 -> bf16 k-major fragment image.
// [e][kc(8)][sub(2)][col(256)][kslot(4)][kk(8)] halfwords: a wave's B-fragment
// is one fully-coalesced 16B/lane load (64 lanes = contiguous 1KB).
// ---------------------------------------------------------------------------
__global__ __launch_bounds__(256) void prep_w2(const float* __restrict__ W2,
                                               unsigned short* __restrict__ ws){
  int idx = blockIdx.x * 256 + threadIdx.x;
  int col = idx & 255;
  int k   = (idx >> 8) & 511;
  int e   = idx >> 17;
  int kc = k >> 6, sub = (k >> 5) & 1, kslot = (k >> 3) & 3, kk = k & 7;
  ws[(((size_t)(e * 8 + kc) * 2 + sub) << 13) + (col << 5) + (kslot << 3) + kk]
      = f2bf(W2[idx]);
}

// ---------------------------------------------------------------------------
// k1: layer1 + LN1 + lrelu -> h1 bf16 [ROWS][512] row-major in ws.
// 256 thr = 32 points, 8 threads/point; thread q owns cols {q*8 + 64j}.
// All stores octet-contiguous (8 lanes x 16B = 128B). No LDS.
// ---------------------------------------------------------------------------
__global__ __launch_bounds__(256) void k1_layer1(
  const float* __restrict__ points, const int* __restrict__ cats,
  const float* __restrict__ W1, const float* __restrict__ b1,
  const float* __restrict__ g1, const float* __restrict__ be1,
  unsigned short* __restrict__ h1g)
{
  const int t = (int)threadIdx.x;
  const int p = t >> 3, q = t & 7;
  const size_t row = (size_t)blockIdx.x * 32 + p;
  const int e = cats[row >> 13];
  const float* pp = points + row * 3;
  const float p0 = pp[0], p1 = pp[1], p2 = pp[2];
  const float* w1a = W1 + (size_t)e * 3 * NH;
  const float* w1b = w1a + NH;
  const float* w1c = w1b + NH;
  const float* b1e = b1 + (size_t)e * NH;

  short8 hr[8];
  float sum = 0.f, ssq = 0.f;
  #pragma unroll
  for(int j = 0; j < 8; j++){
    int c0 = q * 8 + j * 64;
    f32x4 a0 = *(const f32x4*)(w1a + c0), a1 = *(const f32x4*)(w1a + c0 + 4);
    f32x4 u0 = *(const f32x4*)(w1b + c0), u1 = *(const f32x4*)(w1b + c0 + 4);
    f32x4 d0 = *(const f32x4*)(w1c + c0), d1 = *(const f32x4*)(w1c + c0 + 4);
    f32x4 e0 = *(const f32x4*)(b1e + c0), e1 = *(const f32x4*)(b1e + c0 + 4);
    short8 pk;
    #pragma unroll
    for(int i = 0; i < 4; i++){
      float h = fmaf(p0, a0[i], fmaf(p1, u0[i], fmaf(p2, d0[i], e0[i])));
      sum += h; ssq = fmaf(h, h, ssq);
      pk[i] = (short)f2bf(h);
      float h2 = fmaf(p0, a1[i], fmaf(p1, u1[i], fmaf(p2, d1[i], e1[i])));
      sum += h2; ssq = fmaf(h2, h2, ssq);
      pk[4 + i] = (short)f2bf(h2);
    }
    hr[j] = pk;
  }
  sum += __shfl_xor(sum, 1); sum += __shfl_xor(sum, 2); sum += __shfl_xor(sum, 4);
  ssq += __shfl_xor(ssq, 1); ssq += __shfl_xor(ssq, 2); ssq += __shfl_xor(ssq, 4);
  float mu = sum * (1.f / NH);
  float rs = rsqrtf(fmaf(-mu, mu, ssq * (1.f / NH)) + HEPS);
  const float* g1e  = g1  + (size_t)e * NH;
  const float* be1e = be1 + (size_t)e * NH;
  unsigned short* orow = h1g + row * NH;
  #pragma unroll
  for(int j = 0; j < 8; j++){
    int c0 = q * 8 + j * 64;
    f32x4 gg0 = *(const f32x4*)(g1e + c0),  gg1 = *(const f32x4*)(g1e + c0 + 4);
    f32x4 ee0 = *(const f32x4*)(be1e + c0), ee1 = *(const f32x4*)(be1e + c0 + 4);
    short8 v = hr[j], pk;
    #pragma unroll
    for(int i = 0; i < 8; i++){
      float x = bf2f((unsigned short)v[i]);
      float gv = (i < 4) ? gg0[i] : gg1[i - 4];
      float bv = (i < 4) ? ee0[i] : ee1[i - 4];
      x = (x - mu) * rs;
      x = fmaf(x, gv, bv);
      x = (x >= 0.f) ? x : HSLOPE * x;
      pk[i] = (short)f2bf(x);
    }
    *(short8*)(orow + c0) = pk;
  }
}

// ---------------------------------------------------------------------------
// k2: GEMM h2 = h1(64x512 tile) x W2(512x256) + b2, bf16 out.
// 512 thr = 8 waves; wave w owns cols [32w,32w+32). A staged in 2x8KB LDS
// chunks (1 barrier/chunk), B direct from L2 via prep image.
// LDS swizzle (octet-derived): write octet = one row, slots col8^(row&7)
// distinct; read octet = rows 0..7, slots distinct. Conflict-free both ways.
// ---------------------------------------------------------------------------
__global__ __launch_bounds__(512) void k2_gemm(
  const int* __restrict__ cats, const unsigned short* __restrict__ W2s,
  const float* __restrict__ b2, const unsigned short* __restrict__ h1g,
  unsigned short* __restrict__ h2g)
{
  __shared__ unsigned short As[2][64 * 64];   // 2 x 8KB

  const int t    = (int)threadIdx.x;
  const int lane = t & 63;
  const int w    = t >> 6;
  const size_t tile0 = (size_t)blockIdx.x * 64;
  const int e = cats[tile0 >> 13];

  const int bcol  = w * 32 + (lane & 15);
  const int kslot = lane >> 4;
  auto loadB = [&](short8* dst, int kc){
    #pragma unroll
    for(int sub = 0; sub < 2; sub++)
      #pragma unroll
      for(int n = 0; n < 2; n++){
        const unsigned short* p = W2s + (((size_t)(e * 8 + kc) * 2 + sub) << 13)
                                + (((bcol + n * 16) << 5) + (kslot << 3));
        dst[sub * 2 + n] = *(const short8*)p;
      }
  };

  // A-stage coords: thread -> (row ar, 16B-chunk ac) of the 64x64 k-chunk
  const int ar = t >> 3, ac = t & 7;
  const unsigned short* h1row = h1g + (tile0 + ar) * NH + ac * 8;
  const int wAddr = ar * 64 + ((ac ^ (ar & 7)) << 3);

  short8 bA[4], bB[4];
  loadB(bA, 0);
  short8 sreg = *(const short8*)(h1row);          // chunk 0
  *(short8*)(&As[0][wAddr]) = sreg;

  f32x4 acc[4][2];
  #pragma unroll
  for(int m = 0; m < 4; m++)
    #pragma unroll
    for(int n = 0; n < 2; n++){ f32x4 z = {0.f,0.f,0.f,0.f}; acc[m][n] = z; }

  const int arow0 = lane & 15;
  #pragma unroll
  for(int kc = 0; kc < 8; kc++){
    if(kc < 7){
      sreg = *(const short8*)(h1row + (kc + 1) * 64);   // issue next A chunk
      loadB((kc & 1) ? bA : bB, kc + 1);                // issue next B frags
    }
    __syncthreads();                                    // As[kc&1] visible
    short8* bf = (kc & 1) ? bB : bA;
    #pragma unroll
    for(int sub = 0; sub < 2; sub++){
      short8 af[4];
      #pragma unroll
      for(int m = 0; m < 4; m++){
        int row = m * 16 + arow0;
        af[m] = *(const short8*)(&As[kc & 1][row * 64 + ((((sub << 2) + kslot) ^ (row & 7)) << 3)]);
      }
      #pragma unroll
      for(int m = 0; m < 4; m++)
        #pragma unroll
        for(int n = 0; n < 2; n++)
          acc[m][n] = __builtin_amdgcn_mfma_f32_16x16x32_bf16(af[m], bf[sub * 2 + n], acc[m][n], 0, 0, 0);
    }
    if(kc < 7)
      *(short8*)(&As[(kc + 1) & 1][wAddr]) = sreg;      // other buffer: safe
  }

  // epilogue: +b2 -> bf16 h2g
  const float* b2e = b2 + e * 256;
  #pragma unroll
  for(int n = 0; n < 2; n++){
    int col = w * 32 + n * 16 + (lane & 15);
    float bc = b2e[col];
    #pragma unroll
    for(int m = 0; m < 4; m++){
      int row0 = m * 16 + ((lane >> 4) << 2);   // C/D: col=lane&15, row=(l>>4)*4+r
      #pragma unroll
      for(int r = 0; r < 4; r++)
        h2g[(tile0 + row0 + r) * 256 + col] = f2bf(acc[m][n][r] + bc);
    }
  }
}

// ---------------------------------------------------------------------------
// k3: LN2 + lrelu + layer3 -> out. 256 thr = 32 points, 8 thr/point,
// thread q owns cols {q*8 + 64j, j<4}. All loads octet-contiguous.
// ---------------------------------------------------------------------------
__global__ __launch_bounds__(256) void k3_out(
  const int* __restrict__ cats,
  const float* __restrict__ g2, const float* __restrict__ be2,
  const float* __restrict__ W3, const float* __restrict__ b3,
  const unsigned short* __restrict__ h2g, float* __restrict__ out)
{
  const int t = (int)threadIdx.x;
  const int p = t >> 3, q = t & 7;
  const size_t row = (size_t)blockIdx.x * 32 + p;
  const int e = cats[row >> 13];
  const unsigned short* hrow = h2g + row * 256;

  short8 xs[4];
  float s = 0.f, sq = 0.f;
  #pragma unroll
  for(int j = 0; j < 4; j++){
    short8 v = *(const short8*)(hrow + q * 8 + j * 64);
    xs[j] = v;
    #pragma unroll
    for(int i = 0; i < 8; i++){
      float x = bf2f((unsigned short)v[i]);
      s += x; sq = fmaf(x, x, sq);
    }
  }
  s  += __shfl_xor(s, 1);  s  += __shfl_xor(s, 2);  s  += __shfl_xor(s, 4);
  sq += __shfl_xor(sq, 1); sq += __shfl_xor(sq, 2); sq += __shfl_xor(sq, 4);
  float mu = s * (1.f / 256.f);
  float rs = rsqrtf(fmaf(-mu, mu, sq * (1.f / 256.f)) + HEPS);

  float o0 = 0.f, o1 = 0.f, o2 = 0.f;
  #pragma unroll
  for(int j = 0; j < 4; j++){
    int c0 = q * 8 + j * 64;
    f32x4 gg0 = *(const f32x4*)(g2 + (size_t)e * 256 + c0);
    f32x4 gg1 = *(const f32x4*)(g2 + (size_t)e * 256 + c0 + 4);
    f32x4 bb0 = *(const f32x4*)(be2 + (size_t)e * 256 + c0);
    f32x4 bb1 = *(const f32x4*)(be2 + (size_t)e * 256 + c0 + 4);
    const float* w3e = W3 + ((size_t)e * 256 + c0) * 3;   // 24 floats, 16B-aligned
    f32x4 Wv[6];
    #pragma unroll
    for(int u = 0; u < 6; u++) Wv[u] = *(const f32x4*)(w3e + u * 4);
    short8 v = xs[j];
    #pragma unroll
    for(int i = 0; i < 8; i++){
      float x = bf2f((unsigned short)v[i]);
      float gv = (i < 4) ? gg0[i] : gg1[i - 4];
      float bv = (i < 4) ? bb0[i] : bb1[i - 4];
      x = (x - mu) * rs;
      x = fmaf(x, gv, bv);
      x = (x >= 0.f) ? x : HSLOPE * x;
      float w0 = ((const float*)Wv)[i * 3 + 0];
      float w1 = ((const float*)Wv)[i * 3 + 1];
      float w2 = ((const float*)Wv)[i * 3 + 2];
      o0 = fmaf(x, w0, o0); o1 = fmaf(x, w1, o1); o2 = fmaf(x, w2, o2);
    }
  }
  o0 += __shfl_xor(o0, 1); o0 += __shfl_xor(o0, 2); o0 += __shfl_xor(o0, 4);
  o1 += __shfl_xor(o1, 1); o1 += __shfl_xor(o1, 2); o1 += __shfl_xor(o1, 4);
  o2 += __shfl_xor(o2, 1); o2 += __shfl_xor(o2, 2); o2 += __shfl_xor(o2, 4);
  if(q == 0){
    float* op = out + row * 3;
    op[0] = o0 + b3[e * 3 + 0];
    op[1] = o1 + b3[e * 3 + 1];
    op[2] = o2 + b3[e * 3 + 2];
  }
}

// ---------------------------------------------------------------------------
// Tier C fallback: R4 fused kernel with the corrected h1 chunk-XOR swizzle.
// ---------------------------------------------------------------------------
static __device__ __forceinline__ int hw2(int row, int col){
  return (row << 8) + ((((col >> 2) ^ (row & 7)) << 2)) + (col & 3);
}

template<bool PREP>
__global__ __launch_bounds__(512, 2) void fused_mlp(
  const float* __restrict__ points, const int* __restrict__ cats,
  const float* __restrict__ W1, const float* __restrict__ b1,
  const float* __restrict__ g1, const float* __restrict__ be1,
  const float* __restrict__ W2f, const float* __restrict__ b2,
  const float* __restrict__ g2, const float* __restrict__ be2,
  const float* __restrict__ W3, const float* __restrict__ b3,
  const unsigned short* __restrict__ W2s,
  float* __restrict__ out)
{
  __shared__ union SM {
    unsigned short h1[64 * 512];
    float h2[64 * 256];
  } sm;

  const int t    = (int)threadIdx.x;
  const int lane = t & 63;
  const int w    = t >> 6;
  const int bx   = (int)blockIdx.x;
  const int b    = bx >> 7;
  const int n0   = (bx & 127) << 6;
  const int e    = cats[b];

  const int bcol  = w * 32 + (lane & 15);
  const int kslot = lane >> 4;
  auto loadB = [&](short8* dst, int kc){
    if(kc >= 8) return;
    #pragma unroll
    for(int sub = 0; sub < 2; sub++)
      #pragma unroll
      for(int n = 0; n < 2; n++){
        if constexpr (PREP){
          const unsigned short* p = W2s + (((size_t)(e * 8 + kc) * 2 + sub) << 13)
                                  + (((bcol + n * 16) << 5) + (kslot << 3));
          dst[sub * 2 + n] = *(const short8*)p;
        } else {
          const float* p = W2f + (((size_t)e * 512 + kc * 64 + sub * 32 + kslot * 8) << 8)
                         + (bcol + n * 16);
          short8 v;
          #pragma unroll
          for(int kk = 0; kk < 8; kk++) v[kk] = (short)f2bf(p[(size_t)kk << 8]);
          dst[sub * 2 + n] = v;
        }
      }
  };

  short8 bA[4], bB[4];
  loadB(bA, 0);

  {
    const int p = t >> 3, q = t & 7;
    const float* pp = points + (size_t)(b * NN + n0 + p) * 3;
    const float p0 = pp[0], p1 = pp[1], p2 = pp[2];
    const float* w1a = W1 + (size_t)e * 3 * NH;
    const float* w1b = w1a + NH;
    const float* w1c = w1b + NH;
    const float* b1e = b1 + (size_t)e * NH;
    short8 hr[8];
    float sum = 0.f, ssq = 0.f;
    #pragma unroll
    for(int j = 0; j < 8; j++){
      int c0 = q * 64 + j * 8;
      f32x4 a0 = *(const f32x4*)(w1a + c0), a1 = *(const f32x4*)(w1a + c0 + 4);
      f32x4 u0 = *(const f32x4*)(w1b + c0), u1 = *(const f32x4*)(w1b + c0 + 4);
      f32x4 d0 = *(const f32x4*)(w1c + c0), d1 = *(const f32x4*)(w1c + c0 + 4);
      f32x4 e0 = *(const f32x4*)(b1e + c0), e1 = *(const f32x4*)(b1e + c0 + 4);
      short8 pk;
      #pragma unroll
      for(int i = 0; i < 4; i++){
        float h = fmaf(p0, a0[i], fmaf(p1, u0[i], fmaf(p2, d0[i], e0[i])));
        sum += h; ssq = fmaf(h, h, ssq);
        pk[i] = (short)f2bf(h);
        float h2v = fmaf(p0, a1[i], fmaf(p1, u1[i], fmaf(p2, d1[i], e1[i])));
        sum += h2v; ssq = fmaf(h2v, h2v, ssq);
        pk[4 + i] = (short)f2bf(h2v);
      }
      hr[j] = pk;
    }
    sum += __shfl_xor(sum, 1); sum += __shfl_xor(sum, 2); sum += __shfl_xor(sum, 4);
    ssq += __shfl_xor(ssq, 1); ssq += __shfl_xor(ssq, 2); ssq += __shfl_xor(ssq, 4);
    float mu = sum * (1.f / NH);
    float rs = rsqrtf(fmaf(-mu, mu, ssq * (1.f / NH)) + HEPS);
    const float* g1e  = g1  + (size_t)e * NH;
    const float* be1e = be1 + (size_t)e * NH;
    #pragma unroll
    for(int j = 0; j < 8; j++){
      int c0 = q * 64 + j * 8;
      f32x4 gg0 = *(const f32x4*)(g1e + c0),  gg1 = *(const f32x4*)(g1e + c0 + 4);
      f32x4 ee0 = *(const f32x4*)(be1e + c0), ee1 = *(const f32x4*)(be1e + c0 + 4);
      short8 v = hr[j], pk;
      #pragma unroll
      for(int i = 0; i < 8; i++){
        float x = bf2f((unsigned short)v[i]);
        float gv = (i < 4) ? gg0[i] : gg1[i - 4];
        float bv = (i < 4) ? ee0[i] : ee1[i - 4];
        x = (x - mu) * rs;
        x = fmaf(x, gv, bv);
        x = (x >= 0.f) ? x : HSLOPE * x;
        pk[i] = (short)f2bf(x);
      }
      // chunk-XOR swizzle: octet (same p, q varies) -> distinct slots
      *(short8*)(sm.h1 + (p << 9) + (q << 6) + ((j ^ (p & 7) ^ q) << 3)) = pk;
    }
  }
  __syncthreads();

  f32x4 acc[4][2];
  #pragma unroll
  for(int m = 0; m < 4; m++)
    #pragma unroll
    for(int n = 0; n < 2; n++){ f32x4 z = {0.f,0.f,0.f,0.f}; acc[m][n] = z; }

  const int arow0 = lane & 15;
  auto compute = [&](int kc, short8* bf){
    #pragma unroll
    for(int sub = 0; sub < 2; sub++){
      short8 af[4];
      #pragma unroll
      for(int m = 0; m < 4; m++){
        int row = m * 16 + arow0;
        af[m] = *(const short8*)(sm.h1 + (row << 9) + (kc << 6)
                 + ((((sub << 2) + kslot) ^ (row & 7) ^ kc) << 3));
      }
      #pragma unroll
      for(int m = 0; m < 4; m++)
        #pragma unroll
        for(int n = 0; n < 2; n++)
          acc[m][n] = __builtin_amdgcn_mfma_f32_16x16x32_bf16(af[m], bf[sub * 2 + n], acc[m][n], 0, 0, 0);
    }
  };

  #pragma unroll
  for(int kc2 = 0; kc2 < 4; kc2++){
    loadB(bB, kc2 * 2 + 1);
    compute(kc2 * 2, bA);
    loadB(bA, kc2 * 2 + 2);
    compute(kc2 * 2 + 1, bB);
  }

  __syncthreads();

  {
    const float* b2e = b2 + e * 256;
    #pragma unroll
    for(int n = 0; n < 2; n++){
      int col = w * 32 + n * 16 + (lane & 15);
      float bc = b2e[col];
      #pragma unroll
      for(int m = 0; m < 4; m++){
        int row0 = m * 16 + ((lane >> 4) << 2);
        #pragma unroll
        for(int r = 0; r < 4; r++)
          sm.h2[hw2(row0 + r, col)] = acc[m][n][r] + bc;
      }
    }
  }
  __syncthreads();

  {
    const int p = t >> 3, q = t & 7;
    const float* h2base = sm.h2 + (p << 8);
    const int px = p & 7;
    float s = 0.f, sq = 0.f;
    f32x4 xs[8];
    #pragma unroll
    for(int k = 0; k < 8; k++){
      f32x4 v = *(const f32x4*)(h2base + (((8 * k + q) ^ px) << 2));
      xs[k] = v;
      #pragma unroll
      for(int i = 0; i < 4; i++){ s += v[i]; sq = fmaf(v[i], v[i], sq); }
    }
    s  += __shfl_xor(s, 1);  s  += __shfl_xor(s, 2);  s  += __shfl_xor(s, 4);
    sq += __shfl_xor(sq, 1); sq += __shfl_xor(sq, 2); sq += __shfl_xor(sq, 4);
    float mu = s * (1.f / 256.f);
    float rs = rsqrtf(fmaf(-mu, mu, sq * (1.f / 256.f)) + HEPS);
    const float* g2e  = g2  + (size_t)e * 256 + q * 4;
    const float* be2e = be2 + (size_t)e * 256 + q * 4;
    const float* w3e  = W3 + ((size_t)e * 256 + q * 4) * 3;
    float o0 = 0.f, o1 = 0.f, o2 = 0.f;
    #pragma unroll
    for(int k = 0; k < 8; k++){
      f32x4 gg = *(const f32x4*)(g2e + k * 32);
      f32x4 bb = *(const f32x4*)(be2e + k * 32);
      f32x4 W0  = *(const f32x4*)(w3e + k * 96);
      f32x4 W1v = *(const f32x4*)(w3e + k * 96 + 4);
      f32x4 W2v = *(const f32x4*)(w3e + k * 96 + 8);
      f32x4 x = xs[k];
      #pragma unroll
      for(int i = 0; i < 4; i++){
        float xv = (x[i] - mu) * rs;
        xv = fmaf(xv, gg[i], bb[i]);
        x[i] = (xv >= 0.f) ? xv : HSLOPE * xv;
      }
      o0 = fmaf(x[0], W0[0], o0); o1 = fmaf(x[0], W0[1], o1); o2 = fmaf(x[0], W0[2], o2);
      o0 = fmaf(x[1], W0[3], o0); o1 = fmaf(x[1], W1v[0], o1); o2 = fmaf(x[1], W1v[1], o2);
      o0 = fmaf(x[2], W1v[2], o0); o1 = fmaf(x[2], W1v[3], o1); o2 = fmaf(x[2], W2v[0], o2);
      o0 = fmaf(x[3], W2v[1], o0); o1 = fmaf(x[3], W2v[2], o1); o2 = fmaf(x[3], W2v[3], o2);
    }
    o0 += __shfl_xor(o0, 1); o0 += __shfl_xor(o0, 2); o0 += __shfl_xor(o0, 4);
    o1 += __shfl_xor(o1, 1); o1 += __shfl_xor(o1, 2); o1 += __shfl_xor(o1, 4);
    o2 += __shfl_xor(o2, 1); o2 += __shfl_xor(o2, 2); o2 += __shfl_xor(o2, 4);
    if(q == 0){
      float* op = out + (size_t)(b * NN + n0 + p) * 3;
      op[0] = o0 + b3[e * 3 + 0];
      op[1] = o1 + b3[e * 3 + 1];
      op[2] = o2 + b3[e * 3 + 2];
    }
  }
}

extern "C" void kernel_launch(void* const* d_in, const int* in_sizes, int n_in,
                              void* d_out, int out_size, void* d_ws, size_t ws_size,
                              hipStream_t stream) {
  const float* points = (const float*)d_in[0];
  const int*   cats   = (const int*)d_in[1];
  const float* W1  = (const float*)d_in[2];
  const float* b1  = (const float*)d_in[3];
  const float* g1  = (const float*)d_in[4];
  const float* be1 = (const float*)d_in[5];
  const float* W2  = (const float*)d_in[6];
  const float* b2  = (const float*)d_in[7];
  const float* g2  = (const float*)d_in[8];
  const float* be2 = (const float*)d_in[9];
  const float* W3  = (const float*)d_in[10];
  const float* b3  = (const float*)d_in[11];
  float* out = (float*)d_out;

  const size_t W2IMG = (size_t)NE * 512 * 256 * 2;            //   2.62 MB
  const size_t H1SZ  = (size_t)NB * NN * NH * 2;              // 268.44 MB
  const size_t H2SZ  = (size_t)NB * NN * 256 * 2;             // 134.22 MB

  if (ws_size >= W2IMG + H1SZ + H2SZ) {
    unsigned short* wsW2 = (unsigned short*)d_ws;
    unsigned short* h1g  = (unsigned short*)((char*)d_ws + W2IMG);
    unsigned short* h2g  = (unsigned short*)((char*)d_ws + W2IMG + H1SZ);
    prep_w2<<<dim3((NE * 512 * 256) / 256), dim3(256), 0, stream>>>(W2, wsW2);
    k1_layer1<<<dim3(NB * NN / 32), dim3(256), 0, stream>>>(
        points, cats, W1, b1, g1, be1, h1g);
    k2_gemm<<<dim3(NB * NN / 64), dim3(512), 0, stream>>>(
        cats, wsW2, b2, h1g, h2g);
    k3_out<<<dim3(NB * NN / 32), dim3(256), 0, stream>>>(
        cats, g2, be2, W3, b3, h2g, out);
  } else if (ws_size >= W2IMG) {
    unsigned short* wsW2 = (unsigned short*)d_ws;
    prep_w2<<<dim3((NE * 512 * 256) / 256), dim3(256), 0, stream>>>(W2, wsW2);
    fused_mlp<true><<<dim3(NB * (NN / 64)), dim3(512), 0, stream>>>(
        points, cats, W1, b1, g1, be1, W2, b2, g2, be2, W3, b3, wsW2, out);
  } else {
    fused_mlp<false><<<dim3(NB * (NN / 64)), dim3(512), 0, stream>>>(
        points, cats, W1, b1, g1, be1, W2, b2, g2, be2, W3, b3, nullptr, out);
  }
}

// Round 6
// 272.355 us; speedup vs baseline: 1.9189x; 1.9189x over previous
//
#include <hip/hip_runtime.h>
#include <stdint.h>
#include <stddef.h>

#define NB 32
#define NN 8192
#define NH 512
#define NE 10
#define HEPS 1e-5f
#define HSLOPE 0.2f

typedef short short8 __attribute__((ext_vector_type(8)));
typedef float f32x4 __attribute__((ext_vector_type(4)));

static __device__ __forceinline__ unsigned short f2bf(float f){
  unsigned u = __float_as_uint(f);
  u += 0x7FFFu + ((u >> 16) & 1u);   // RNE
  return (unsigned short)(u >> 16);
}
static __device__ __forceinline__ float bf2f(unsigned short h){
  return __uint_as_float(((unsigned)h) << 16);
}

// ---------------------------------------------------------------------------
// Prep: W2 [E][512][256] f32 -> bf16 k-major fragment image (proven R2-R5).
// [e][kc(8)][sub(2)][col(256)][kslot(4)][kk(8)]: a wave's B-frag is one
// coalesced 16B/lane load (64 lanes = contiguous 1KB).
// ---------------------------------------------------------------------------
__global__ __launch_bounds__(256) void prep_w2(const float* __restrict__ W2,
                                               unsigned short* __restrict__ ws){
  int idx = blockIdx.x * 256 + threadIdx.x;
  int col = idx & 255;
  int k   = (idx >> 8) & 511;
  int e   = idx >> 17;
  int kc = k >> 6, sub = (k >> 5) & 1, kslot = (k >> 3) & 3, kk = k & 7;
  ws[(((size_t)(e * 8 + kc) * 2 + sub) << 13) + (col << 5) + (kslot << 3) + kk]
      = f2bf(W2[idx]);
}

// ---------------------------------------------------------------------------
// Main kernel: block = 64 rows, 4 waves; wave = 64 rows x 64 cols GEMM tile.
//  L1 : each wave computes k-quarter of layer1 DIRECTLY in MFMA frag layout
//       (lane fr=row%16, ks=kslot), pre-LN bf16 in regs; cross-wave LN1
//       stats via 2KB LDS; normalized frags -> frag-major 64KB LDS A-buffer
//       (every LDS access = 64 lanes x contiguous 16B: conflict-free by
//       construction).
//  GEMM: 16 unrolled barrier-free k-steps; A 2-deep from LDS, B 3-deep from
//       L2 (prep image); 16 independent MFMAs per step.
//  EPI : +b2 -> LN2 stats in-reg (shfl over 16 col-lanes) + cross-wave LDS;
//       normalize + lrelu + layer3 partials in-reg; shfl + LDS reduce -> out.
// LDS 66KB -> 2 blocks/CU. No data round-trips through swizzled layouts.
// ---------------------------------------------------------------------------
template<bool PREP>
__global__ __launch_bounds__(256) void mlp_main(
  const float* __restrict__ points, const int* __restrict__ cats,
  const float* __restrict__ W1, const float* __restrict__ b1,
  const float* __restrict__ g1, const float* __restrict__ be1,
  const float* __restrict__ W2f, const float* __restrict__ b2,
  const float* __restrict__ g2, const float* __restrict__ be2,
  const float* __restrict__ W3, const float* __restrict__ b3,
  const unsigned short* __restrict__ W2s,
  float* __restrict__ out)
{
  __shared__ unsigned short As[64 * 512];   // frag-major: frag(m,t) at (m*16+t)*512 + lane*8
  __shared__ float st[64][4][2];            // per-row cross-wave stats (LN1, then LN2)

  const int tid  = (int)threadIdx.x;
  const int lane = tid & 63;
  const int w    = tid >> 6;              // wave 0..3
  const int fr   = lane & 15;
  const int ks   = lane >> 4;
  const size_t row0 = (size_t)blockIdx.x * 64;
  const int e = cats[row0 >> 13];
  const int wbase = w * 64;               // wave's 64-col slice

  // ---------------- layer1 + LN1 + lrelu -> A frags ----------------
  {
    const float* W1e = W1 + (size_t)e * 3 * NH;
    const float* b1e = b1 + (size_t)e * NH;
    float px[4], py[4], pz[4];
    #pragma unroll
    for(int m = 0; m < 4; m++){
      const float* pp = points + (row0 + m * 16 + fr) * 3;
      px[m] = pp[0]; py[m] = pp[1]; pz[m] = pp[2];
    }
    float s1[4] = {0,0,0,0}, q1[4] = {0,0,0,0};
    short8 afr[4][4];                     // [m][tt] pre-LN bf16
    #pragma unroll
    for(int tt = 0; tt < 4; tt++){
      int k0 = (w * 4 + tt) * 32 + ks * 8;
      f32x4 wa0 = *(const f32x4*)(W1e + k0),        wa1 = *(const f32x4*)(W1e + k0 + 4);
      f32x4 wb0 = *(const f32x4*)(W1e + NH + k0),   wb1 = *(const f32x4*)(W1e + NH + k0 + 4);
      f32x4 wc0 = *(const f32x4*)(W1e + 2*NH + k0), wc1 = *(const f32x4*)(W1e + 2*NH + k0 + 4);
      f32x4 bb0 = *(const f32x4*)(b1e + k0),        bb1 = *(const f32x4*)(b1e + k0 + 4);
      #pragma unroll
      for(int m = 0; m < 4; m++){
        short8 pk;
        #pragma unroll
        for(int i = 0; i < 4; i++){
          float h0 = fmaf(px[m], wa0[i], fmaf(py[m], wb0[i], fmaf(pz[m], wc0[i], bb0[i])));
          s1[m] += h0; q1[m] = fmaf(h0, h0, q1[m]);
          pk[i] = (short)f2bf(h0);
          float h1v = fmaf(px[m], wa1[i], fmaf(py[m], wb1[i], fmaf(pz[m], wc1[i], bb1[i])));
          s1[m] += h1v; q1[m] = fmaf(h1v, h1v, q1[m]);
          pk[4 + i] = (short)f2bf(h1v);
        }
        afr[m][tt] = pk;
      }
    }
    // intra-wave: sum over ks lanes (same fr = same row)
    #pragma unroll
    for(int m = 0; m < 4; m++){
      s1[m] += __shfl_xor(s1[m], 16); s1[m] += __shfl_xor(s1[m], 32);
      q1[m] += __shfl_xor(q1[m], 16); q1[m] += __shfl_xor(q1[m], 32);
    }
    if(ks == 0){
      #pragma unroll
      for(int m = 0; m < 4; m++){
        st[m * 16 + fr][w][0] = s1[m];
        st[m * 16 + fr][w][1] = q1[m];
      }
    }
    __syncthreads();
    float al[4], bt[4];
    #pragma unroll
    for(int m = 0; m < 4; m++){
      float ssum = 0.f, qsum = 0.f;
      #pragma unroll
      for(int ww = 0; ww < 4; ww++){ ssum += st[m * 16 + fr][ww][0]; qsum += st[m * 16 + fr][ww][1]; }
      float mu = ssum * (1.f / NH);
      float rs = rsqrtf(fmaf(-mu, mu, qsum * (1.f / NH)) + HEPS);
      al[m] = rs; bt[m] = -mu * rs;
    }
    const float* g1e  = g1  + (size_t)e * NH;
    const float* be1e = be1 + (size_t)e * NH;
    #pragma unroll
    for(int tt = 0; tt < 4; tt++){
      int k0 = (w * 4 + tt) * 32 + ks * 8;
      f32x4 gg0 = *(const f32x4*)(g1e + k0),  gg1 = *(const f32x4*)(g1e + k0 + 4);
      f32x4 ee0 = *(const f32x4*)(be1e + k0), ee1 = *(const f32x4*)(be1e + k0 + 4);
      #pragma unroll
      for(int m = 0; m < 4; m++){
        short8 v = afr[m][tt], pk;
        #pragma unroll
        for(int i = 0; i < 8; i++){
          float x = bf2f((unsigned short)v[i]);
          float gv = (i < 4) ? gg0[i] : gg1[i - 4];
          float bv = (i < 4) ? ee0[i] : ee1[i - 4];
          float y = fmaf(fmaf(x, al[m], bt[m]), gv, bv);
          y = fmaxf(y, HSLOPE * y);       // leaky relu
          pk[i] = (short)f2bf(y);
        }
        *(short8*)(&As[(m * 16 + w * 4 + tt) * 512 + lane * 8]) = pk;
      }
    }
  }

  // B-frag loader (4 n-frags for k-step t)
  auto loadB = [&](short8* dst, int t){
    int kc = t >> 1, sub = t & 1;
    #pragma unroll
    for(int n = 0; n < 4; n++){
      if constexpr (PREP){
        const unsigned short* p = W2s + (((size_t)(e * 8 + kc) * 2 + sub) << 13)
                                + (((wbase + n * 16 + fr) << 5) + (ks << 3));
        dst[n] = *(const short8*)p;
      } else {
        const float* p = W2f + (((size_t)e * 512 + t * 32 + ks * 8) << 8)
                       + (wbase + n * 16 + fr);
        short8 v;
        #pragma unroll
        for(int kk = 0; kk < 8; kk++) v[kk] = (short)f2bf(p[(size_t)kk << 8]);
        dst[n] = v;
      }
    }
  };

  short8 bfr[3][4];
  loadB(bfr[0], 0);            // issue before barrier: hides L2 latency
  loadB(bfr[1], 1);
  __syncthreads();             // A-buffer ready

  // ---------------- GEMM: 16 barrier-free k-steps ----------------
  f32x4 acc[4][4];
  #pragma unroll
  for(int m = 0; m < 4; m++)
    #pragma unroll
    for(int n = 0; n < 4; n++){ f32x4 z = {0.f,0.f,0.f,0.f}; acc[m][n] = z; }

  short8 afrag[2][4];
  #pragma unroll
  for(int m = 0; m < 4; m++)
    afrag[0][m] = *(const short8*)(&As[(m * 16 + 0) * 512 + lane * 8]);

  #pragma unroll
  for(int t = 0; t < 16; t++){
    if(t < 14) loadB(bfr[(t + 2) % 3], t + 2);
    if(t < 15){
      #pragma unroll
      for(int m = 0; m < 4; m++)
        afrag[(t + 1) & 1][m] = *(const short8*)(&As[(m * 16 + t + 1) * 512 + lane * 8]);
    }
    #pragma unroll
    for(int m = 0; m < 4; m++)
      #pragma unroll
      for(int n = 0; n < 4; n++)
        acc[m][n] = __builtin_amdgcn_mfma_f32_16x16x32_bf16(
            afrag[t & 1][m], bfr[t % 3][n], acc[m][n], 0, 0, 0);
  }

  __syncthreads();             // all waves done with As (opart overlays it)

  // ---------------- epilogue: +b2, LN2, lrelu, layer3 ----------------
  {
    const float* b2e = b2 + e * 256;
    float bcv[4];
    #pragma unroll
    for(int n = 0; n < 4; n++) bcv[n] = b2e[wbase + n * 16 + fr];
    #pragma unroll
    for(int m = 0; m < 4; m++)
      #pragma unroll
      for(int n = 0; n < 4; n++)
        #pragma unroll
        for(int r = 0; r < 4; r++)
          acc[m][n][r] += bcv[n];

    // per-row partial stats over this wave's 64 cols
    float s2[4][4], q2[4][4];
    #pragma unroll
    for(int m = 0; m < 4; m++)
      #pragma unroll
      for(int r = 0; r < 4; r++){
        float s = 0.f, q = 0.f;
        #pragma unroll
        for(int n = 0; n < 4; n++){ float x = acc[m][n][r]; s += x; q = fmaf(x, x, q); }
        #pragma unroll
        for(int d = 1; d < 16; d <<= 1){ s += __shfl_xor(s, d); q += __shfl_xor(q, d); }
        s2[m][r] = s; q2[m][r] = q;
      }
    if(fr == 0){
      #pragma unroll
      for(int m = 0; m < 4; m++)
        #pragma unroll
        for(int r = 0; r < 4; r++){
          st[m * 16 + ks * 4 + r][w][0] = s2[m][r];
          st[m * 16 + ks * 4 + r][w][1] = q2[m][r];
        }
    }
    __syncthreads();

    float al2[4][4], bt2[4][4];
    #pragma unroll
    for(int m = 0; m < 4; m++)
      #pragma unroll
      for(int r = 0; r < 4; r++){
        int row = m * 16 + ks * 4 + r;
        float ssum = 0.f, qsum = 0.f;
        #pragma unroll
        for(int ww = 0; ww < 4; ww++){ ssum += st[row][ww][0]; qsum += st[row][ww][1]; }
        float mu = ssum * (1.f / 256.f);
        float rs = rsqrtf(fmaf(-mu, mu, qsum * (1.f / 256.f)) + HEPS);
        al2[m][r] = rs; bt2[m][r] = -mu * rs;
      }

    const float* g2e  = g2  + (size_t)e * 256;
    const float* be2e = be2 + (size_t)e * 256;
    const float* W3e  = W3 + (size_t)e * 256 * 3;
    float o[4][4][3];
    #pragma unroll
    for(int m = 0; m < 4; m++)
      #pragma unroll
      for(int r = 0; r < 4; r++){ o[m][r][0] = 0.f; o[m][r][1] = 0.f; o[m][r][2] = 0.f; }
    #pragma unroll
    for(int n = 0; n < 4; n++){
      int col = wbase + n * 16 + fr;
      float gv = g2e[col], bv = be2e[col];
      float w30 = W3e[col * 3 + 0], w31 = W3e[col * 3 + 1], w32 = W3e[col * 3 + 2];
      #pragma unroll
      for(int m = 0; m < 4; m++)
        #pragma unroll
        for(int r = 0; r < 4; r++){
          float x = fmaf(acc[m][n][r], al2[m][r], bt2[m][r]);
          x = fmaf(x, gv, bv);
          x = fmaxf(x, HSLOPE * x);
          o[m][r][0] = fmaf(x, w30, o[m][r][0]);
          o[m][r][1] = fmaf(x, w31, o[m][r][1]);
          o[m][r][2] = fmaf(x, w32, o[m][r][2]);
        }
    }
    // reduce over 16 col-lanes
    #pragma unroll
    for(int m = 0; m < 4; m++)
      #pragma unroll
      for(int r = 0; r < 4; r++)
        #pragma unroll
        for(int c = 0; c < 3; c++){
          float v = o[m][r][c];
          #pragma unroll
          for(int d = 1; d < 16; d <<= 1) v += __shfl_xor(v, d);
          o[m][r][c] = v;
        }
    float* opart = (float*)As;   // [64][4][3] overlay (As dead)
    if(fr == 0){
      #pragma unroll
      for(int m = 0; m < 4; m++)
        #pragma unroll
        for(int r = 0; r < 4; r++)
          #pragma unroll
          for(int c = 0; c < 3; c++)
            opart[((m * 16 + ks * 4 + r) * 4 + w) * 3 + c] = o[m][r][c];
    }
    __syncthreads();
    if(tid < 192){
      int rr = tid / 3, c = tid - rr * 3;
      float v = b3[e * 3 + c];
      #pragma unroll
      for(int ww = 0; ww < 4; ww++) v += opart[(rr * 4 + ww) * 3 + c];
      out[(row0 + rr) * 3 + c] = v;
    }
  }
}

extern "C" void kernel_launch(void* const* d_in, const int* in_sizes, int n_in,
                              void* d_out, int out_size, void* d_ws, size_t ws_size,
                              hipStream_t stream) {
  const float* points = (const float*)d_in[0];
  const int*   cats   = (const int*)d_in[1];
  const float* W1  = (const float*)d_in[2];
  const float* b1  = (const float*)d_in[3];
  const float* g1  = (const float*)d_in[4];
  const float* be1 = (const float*)d_in[5];
  const float* W2  = (const float*)d_in[6];
  const float* b2  = (const float*)d_in[7];
  const float* g2  = (const float*)d_in[8];
  const float* be2 = (const float*)d_in[9];
  const float* W3  = (const float*)d_in[10];
  const float* b3  = (const float*)d_in[11];
  float* out = (float*)d_out;

  const size_t W2IMG = (size_t)NE * 512 * 256 * 2;   // 2.62 MB bf16 image
  const int grid = NB * NN / 64;                     // 4096 blocks

  if (ws_size >= W2IMG) {
    unsigned short* wsW2 = (unsigned short*)d_ws;
    prep_w2<<<dim3((NE * 512 * 256) / 256), dim3(256), 0, stream>>>(W2, wsW2);
    mlp_main<true><<<dim3(grid), dim3(256), 0, stream>>>(
        points, cats, W1, b1, g1, be1, W2, b2, g2, be2, W3, b3, wsW2, out);
  } else {
    mlp_main<false><<<dim3(grid), dim3(256), 0, stream>>>(
        points, cats, W1, b1, g1, be1, W2, b2, g2, be2, W3, b3, nullptr, out);
  }
}

// Round 7
// 204.223 us; speedup vs baseline: 2.5591x; 1.3336x over previous
//
#include <hip/hip_runtime.h>
#include <stdint.h>
#include <stddef.h>

#define NB 32
#define NN 8192
#define NH 512
#define NE 10
#define HEPS 1e-5f
#define HSLOPE 0.2f

typedef short short8 __attribute__((ext_vector_type(8)));
typedef float f32x4 __attribute__((ext_vector_type(4)));

static __device__ __forceinline__ unsigned short f2bf(float f){
  unsigned u = __float_as_uint(f);
  u += 0x7FFFu + ((u >> 16) & 1u);   // RNE
  return (unsigned short)(u >> 16);
}

// ---------------------------------------------------------------------------
// Prep: W2 [E][512][256] f32 -> bf16 k-major fragment image (proven R2-R6).
// [e][kc(8)][sub(2)][col(256)][kslot(4)][kk(8)]: a wave's B-frag is one
// coalesced 16B/lane load (64 lanes = contiguous 1KB).
// ---------------------------------------------------------------------------
__global__ __launch_bounds__(256) void prep_w2(const float* __restrict__ W2,
                                               unsigned short* __restrict__ ws){
  int idx = blockIdx.x * 256 + threadIdx.x;
  int col = idx & 255;
  int k   = (idx >> 8) & 511;
  int e   = idx >> 17;
  int kc = k >> 6, sub = (k >> 5) & 1, kslot = (k >> 3) & 3, kk = k & 7;
  ws[(((size_t)(e * 8 + kc) * 2 + sub) << 13) + (col << 5) + (kslot << 3) + kk]
      = f2bf(W2[idx]);
}

// ---------------------------------------------------------------------------
// Main: block = 32 rows, 4 waves. LDS = 32KB frag-major A + 1KB stats
// -> 3 blocks/CU (vs R6's 1). Layer1 is now MFMA (bias folded as k=3).
//  L1  : h[32x512] = mfma(points_frag, W1_frag); wave w computes cols
//        [w*128,w*128+128) (8 n-frags x 2 m-frags, 1 k-step). LN1 stats from
//        fp32 acc (shfl over fr + cross-wave st). Normalize+lrelu in C/D
//        layout -> bf16 ds_write_b16 scatter into frag-major As.
//        Mapping (verified): value(row=m2*16+ks4*4+r, k=w*128+n2*16+fr) ->
//        As[F*512 + (n2&1)*256 + (fr>>3)*128 + ks4*32 + r*8 + (fr&7)],
//        F = (w*4 + (n2>>1))*2 + m2.  GEMM reads frag F at lane*8: row=
//        m*16+(lane&15), k=t*32+(lane>>4)*8+kk with t=F>>1, m=F&1. Identity
//        checked: addr 1993 <-> (row 25, k 57) both sides.
//  GEMM: wave tile 32x64: 16 k-steps x (2m x 4n) MFMA; A 2-deep from LDS
//        (contiguous 1KB frags, conflict-free), B 3-deep from L2 prep image.
//  EPI : +b2, LN2 (in-reg + cross-wave st), lrelu, layer3 partials in-reg,
//        fr-shfl reduce, cross-wave via 1.5KB opart overlay on As.
// ---------------------------------------------------------------------------
template<bool PREP>
__global__ __launch_bounds__(256, 3) void mlp_main(
  const float* __restrict__ points, const int* __restrict__ cats,
  const float* __restrict__ W1, const float* __restrict__ b1,
  const float* __restrict__ g1, const float* __restrict__ be1,
  const float* __restrict__ W2f, const float* __restrict__ b2,
  const float* __restrict__ g2, const float* __restrict__ be2,
  const float* __restrict__ W3, const float* __restrict__ b3,
  const unsigned short* __restrict__ W2s,
  float* __restrict__ out)
{
  __shared__ unsigned short As[32 * 512];            // 32KB frag-major
  __shared__ __align__(16) float st[32][4][2];       // 1KB cross-wave stats

  const int tid  = (int)threadIdx.x;
  const int lane = tid & 63;
  const int w    = tid >> 6;            // wave 0..3
  const int fr   = lane & 15;
  const int ks4  = lane >> 4;           // k-slot 0..3
  const size_t row0 = (size_t)blockIdx.x * 32;
  const int e = cats[row0 >> 13];

  // ---------------- layer1 via MFMA ----------------
  float al1[2][4], bt1[2][4];
  f32x4 a1[2][8];
  {
    const float* W1e = W1 + (size_t)e * 3 * NH;
    const float* b1e = b1 + (size_t)e * NH;
    // A-frags from points; k-slot 3 carries the bias multiplier 1.0
    short8 apf[2];
    #pragma unroll
    for(int m2 = 0; m2 < 2; m2++){
      const float* pp = points + (row0 + m2 * 16 + fr) * 3;
      float P0 = pp[0], P1 = pp[1], P2 = pp[2];
      short8 v = {0,0,0,0,0,0,0,0};
      if(ks4 == 0){
        v[0] = (short)f2bf(P0); v[1] = (short)f2bf(P1);
        v[2] = (short)f2bf(P2); v[3] = (short)0x3F80;   // bf16 1.0
      }
      apf[m2] = v;
    }
    #pragma unroll
    for(int n2 = 0; n2 < 8; n2++){
      int col = w * 128 + n2 * 16 + fr;
      short8 bw = {0,0,0,0,0,0,0,0};
      bw[0] = (short)f2bf(W1e[col]);
      bw[1] = (short)f2bf(W1e[NH + col]);
      bw[2] = (short)f2bf(W1e[2 * NH + col]);
      bw[3] = (short)f2bf(b1e[col]);
      #pragma unroll
      for(int m2 = 0; m2 < 2; m2++){
        f32x4 z = {0.f, 0.f, 0.f, 0.f};
        a1[m2][n2] = __builtin_amdgcn_mfma_f32_16x16x32_bf16(apf[m2], bw, z, 0, 0, 0);
      }
    }
    // LN1 stats: per (m2,r) over this wave's 128 cols, then cross-wave
    #pragma unroll
    for(int m2 = 0; m2 < 2; m2++)
      #pragma unroll
      for(int r = 0; r < 4; r++){
        float s = 0.f, q = 0.f;
        #pragma unroll
        for(int n2 = 0; n2 < 8; n2++){ float x = a1[m2][n2][r]; s += x; q = fmaf(x, x, q); }
        s += __shfl_xor(s, 1); s += __shfl_xor(s, 2); s += __shfl_xor(s, 4); s += __shfl_xor(s, 8);
        q += __shfl_xor(q, 1); q += __shfl_xor(q, 2); q += __shfl_xor(q, 4); q += __shfl_xor(q, 8);
        if(fr == 0){
          st[m2 * 16 + ks4 * 4 + r][w][0] = s;
          st[m2 * 16 + ks4 * 4 + r][w][1] = q;
        }
      }
    __syncthreads();
    #pragma unroll
    for(int m2 = 0; m2 < 2; m2++)
      #pragma unroll
      for(int r = 0; r < 4; r++){
        int row = m2 * 16 + ks4 * 4 + r;
        f32x4 v0 = *(const f32x4*)&st[row][0][0];
        f32x4 v1 = *(const f32x4*)&st[row][2][0];
        float ssum = v0[0] + v0[2] + v1[0] + v1[2];
        float qsum = v0[1] + v0[3] + v1[1] + v1[3];
        float mu = ssum * (1.f / NH);
        float rs = rsqrtf(fmaf(-mu, mu, qsum * (1.f / NH)) + HEPS);
        al1[m2][r] = rs; bt1[m2][r] = -mu * rs;
      }
  }

  // normalize + lrelu -> bf16 scatter into frag-major As
  {
    const float* g1e  = g1  + (size_t)e * NH;
    const float* be1e = be1 + (size_t)e * NH;
    const int laneoff = ((fr >> 3) << 7) + (ks4 << 5) + (fr & 7);
    #pragma unroll
    for(int n2 = 0; n2 < 8; n2++){
      int col = w * 128 + n2 * 16 + fr;
      float gv = g1e[col], bv = be1e[col];
      #pragma unroll
      for(int m2 = 0; m2 < 2; m2++){
        int F = (w * 4 + (n2 >> 1)) * 2 + m2;
        int base = (F << 9) + ((n2 & 1) << 8) + laneoff;
        #pragma unroll
        for(int r = 0; r < 4; r++){
          float x = fmaf(a1[m2][n2][r], al1[m2][r], bt1[m2][r]);
          x = fmaf(x, gv, bv);
          x = fmaxf(x, HSLOPE * x);
          As[base + (r << 3)] = f2bf(x);
        }
      }
    }
  }

  // ---------------- B prefetch (L2, prep image) ----------------
  const int wbase = w * 64;
  auto loadB = [&](short8* dst, int t){
    int kc = t >> 1, sub = t & 1;
    #pragma unroll
    for(int n = 0; n < 4; n++){
      if constexpr (PREP){
        const unsigned short* p = W2s + (((size_t)(e * 8 + kc) * 2 + sub) << 13)
                                + (((wbase + n * 16 + fr) << 5) + (ks4 << 3));
        dst[n] = *(const short8*)p;
      } else {
        const float* p = W2f + (((size_t)e * 512 + t * 32 + ks4 * 8) << 8)
                       + (wbase + n * 16 + fr);
        short8 v;
        #pragma unroll
        for(int kk = 0; kk < 8; kk++) v[kk] = (short)f2bf(p[(size_t)kk << 8]);
        dst[n] = v;
      }
    }
  };
  short8 bfr[3][4];
  loadB(bfr[0], 0); loadB(bfr[1], 1); loadB(bfr[2], 2);

  __syncthreads();   // As complete

  // ---------------- GEMM: 16 barrier-free k-steps ----------------
  f32x4 acc[2][4];
  #pragma unroll
  for(int m = 0; m < 2; m++)
    #pragma unroll
    for(int n = 0; n < 4; n++){ f32x4 z = {0.f,0.f,0.f,0.f}; acc[m][n] = z; }

  auto loadA = [&](short8* dst, int t){
    dst[0] = *(const short8*)&As[((t * 2 + 0) << 9) + lane * 8];
    dst[1] = *(const short8*)&As[((t * 2 + 1) << 9) + lane * 8];
  };
  short8 afA[2], afB[2];
  loadA(afA, 0);

  #pragma unroll
  for(int t = 0; t < 16; t++){
    short8* af = (t & 1) ? afB : afA;
    if(t < 15) loadA((t & 1) ? afA : afB, t + 1);
    #pragma unroll
    for(int m = 0; m < 2; m++)
      #pragma unroll
      for(int n = 0; n < 4; n++)
        acc[m][n] = __builtin_amdgcn_mfma_f32_16x16x32_bf16(af[m], bfr[t % 3][n], acc[m][n], 0, 0, 0);
    if(t < 13) loadB(bfr[t % 3], t + 3);
  }

  // ---------------- epilogue ----------------
  {
    const float* b2e = b2 + e * 256;
    float bcv[4];
    #pragma unroll
    for(int n = 0; n < 4; n++) bcv[n] = b2e[wbase + n * 16 + fr];
    #pragma unroll
    for(int m = 0; m < 2; m++)
      #pragma unroll
      for(int n = 0; n < 4; n++)
        #pragma unroll
        for(int r = 0; r < 4; r++)
          acc[m][n][r] += bcv[n];

    // LN2 stats
    #pragma unroll
    for(int m = 0; m < 2; m++)
      #pragma unroll
      for(int r = 0; r < 4; r++){
        float s = 0.f, q = 0.f;
        #pragma unroll
        for(int n = 0; n < 4; n++){ float x = acc[m][n][r]; s += x; q = fmaf(x, x, q); }
        s += __shfl_xor(s, 1); s += __shfl_xor(s, 2); s += __shfl_xor(s, 4); s += __shfl_xor(s, 8);
        q += __shfl_xor(q, 1); q += __shfl_xor(q, 2); q += __shfl_xor(q, 4); q += __shfl_xor(q, 8);
        if(fr == 0){
          st[m * 16 + ks4 * 4 + r][w][0] = s;
          st[m * 16 + ks4 * 4 + r][w][1] = q;
        }
      }
    __syncthreads();
    float al2[2][4], bt2[2][4];
    #pragma unroll
    for(int m = 0; m < 2; m++)
      #pragma unroll
      for(int r = 0; r < 4; r++){
        int row = m * 16 + ks4 * 4 + r;
        f32x4 v0 = *(const f32x4*)&st[row][0][0];
        f32x4 v1 = *(const f32x4*)&st[row][2][0];
        float ssum = v0[0] + v0[2] + v1[0] + v1[2];
        float qsum = v0[1] + v0[3] + v1[1] + v1[3];
        float mu = ssum * (1.f / 256.f);
        float rs = rsqrtf(fmaf(-mu, mu, qsum * (1.f / 256.f)) + HEPS);
        al2[m][r] = rs; bt2[m][r] = -mu * rs;
      }

    const float* g2e  = g2  + (size_t)e * 256;
    const float* be2e = be2 + (size_t)e * 256;
    const float* W3e  = W3 + (size_t)e * 256 * 3;
    float o[2][4][3];
    #pragma unroll
    for(int m = 0; m < 2; m++)
      #pragma unroll
      for(int r = 0; r < 4; r++){ o[m][r][0] = 0.f; o[m][r][1] = 0.f; o[m][r][2] = 0.f; }
    #pragma unroll
    for(int n = 0; n < 4; n++){
      int col = wbase + n * 16 + fr;
      float gv = g2e[col], bv = be2e[col];
      float w30 = W3e[col * 3 + 0], w31 = W3e[col * 3 + 1], w32 = W3e[col * 3 + 2];
      #pragma unroll
      for(int m = 0; m < 2; m++)
        #pragma unroll
        for(int r = 0; r < 4; r++){
          float x = fmaf(acc[m][n][r], al2[m][r], bt2[m][r]);
          x = fmaf(x, gv, bv);
          x = fmaxf(x, HSLOPE * x);
          o[m][r][0] = fmaf(x, w30, o[m][r][0]);
          o[m][r][1] = fmaf(x, w31, o[m][r][1]);
          o[m][r][2] = fmaf(x, w32, o[m][r][2]);
        }
    }
    #pragma unroll
    for(int m = 0; m < 2; m++)
      #pragma unroll
      for(int r = 0; r < 4; r++)
        #pragma unroll
        for(int c = 0; c < 3; c++){
          float v = o[m][r][c];
          v += __shfl_xor(v, 1); v += __shfl_xor(v, 2);
          v += __shfl_xor(v, 4); v += __shfl_xor(v, 8);
          o[m][r][c] = v;
        }
    float* opart = (float*)As;   // 32*4*3 floats overlay; As dead after GEMM
    if(fr == 0){
      #pragma unroll
      for(int m = 0; m < 2; m++)
        #pragma unroll
        for(int r = 0; r < 4; r++)
          #pragma unroll
          for(int c = 0; c < 3; c++)
            opart[((m * 16 + ks4 * 4 + r) * 4 + w) * 3 + c] = o[m][r][c];
    }
    __syncthreads();
    if(tid < 96){
      int rr = tid / 3, c = tid - rr * 3;
      float v = b3[e * 3 + c];
      #pragma unroll
      for(int ww = 0; ww < 4; ww++) v += opart[(rr * 4 + ww) * 3 + c];
      out[(row0 + rr) * 3 + c] = v;
    }
  }
}

extern "C" void kernel_launch(void* const* d_in, const int* in_sizes, int n_in,
                              void* d_out, int out_size, void* d_ws, size_t ws_size,
                              hipStream_t stream) {
  const float* points = (const float*)d_in[0];
  const int*   cats   = (const int*)d_in[1];
  const float* W1  = (const float*)d_in[2];
  const float* b1  = (const float*)d_in[3];
  const float* g1  = (const float*)d_in[4];
  const float* be1 = (const float*)d_in[5];
  const float* W2  = (const float*)d_in[6];
  const float* b2  = (const float*)d_in[7];
  const float* g2  = (const float*)d_in[8];
  const float* be2 = (const float*)d_in[9];
  const float* W3  = (const float*)d_in[10];
  const float* b3  = (const float*)d_in[11];
  float* out = (float*)d_out;

  const size_t W2IMG = (size_t)NE * 512 * 256 * 2;   // 2.62 MB bf16 image
  const int grid = NB * NN / 32;                     // 8192 blocks

  if (ws_size >= W2IMG) {
    unsigned short* wsW2 = (unsigned short*)d_ws;
    prep_w2<<<dim3((NE * 512 * 256) / 256), dim3(256), 0, stream>>>(W2, wsW2);
    mlp_main<true><<<dim3(grid), dim3(256), 0, stream>>>(
        points, cats, W1, b1, g1, be1, W2, b2, g2, be2, W3, b3, wsW2, out);
  } else {
    mlp_main<false><<<dim3(grid), dim3(256), 0, stream>>>(
        points, cats, W1, b1, g1, be1, W2, b2, g2, be2, W3, b3, nullptr, out);
  }
}

// Round 8
// 202.122 us; speedup vs baseline: 2.5857x; 1.0104x over previous
//
#include <hip/hip_runtime.h>
#include <hip/hip_bf16.h>
#include <stdint.h>
#include <stddef.h>

#define NB 32
#define NN 8192
#define NH 512
#define NE 10
#define HEPS 1e-5f
#define HSLOPE 0.2f

typedef short short8 __attribute__((ext_vector_type(8)));
typedef float f32x4 __attribute__((ext_vector_type(4)));

// Hardware bf16 converts (v_cvt_pk_bf16_f32 via compiler) — not manual RNE.
static __device__ __forceinline__ unsigned short sbf(float a){
  __hip_bfloat16 t = __float2bfloat16(a);
  return *reinterpret_cast<unsigned short*>(&t);
}
static __device__ __forceinline__ unsigned pkbf(float a, float b){
  float2 f2; f2.x = a; f2.y = b;
  __hip_bfloat162 t = __float22bfloat162_rn(f2);
  return *reinterpret_cast<unsigned*>(&t);
}

// ---------------------------------------------------------------------------
// Prep: W2 [E][512][256] f32 -> bf16 k-major fragment image (proven R2-R7).
// [e][kc(8)][sub(2)][col(256)][kslot(4)][kk(8)]: a wave's B-frag is one
// coalesced 16B/lane load (64 lanes = contiguous 1KB).
// ---------------------------------------------------------------------------
__global__ __launch_bounds__(256) void prep_w2(const float* __restrict__ W2,
                                               unsigned short* __restrict__ ws){
  int idx = blockIdx.x * 256 + threadIdx.x;
  int col = idx & 255;
  int k   = (idx >> 8) & 511;
  int e   = idx >> 17;
  int kc = k >> 6, sub = (k >> 5) & 1, kslot = (k >> 3) & 3, kk = k & 7;
  ws[(((size_t)(e * 8 + kc) * 2 + sub) << 13) + (col << 5) + (kslot << 3) + kk]
      = sbf(W2[idx]);
}

// ---------------------------------------------------------------------------
// Main: block = 32 rows, 4 waves, LDS 33.8KB -> 4 blocks/CU. (R7 structure.)
//  L1  : layer1 via MFMA (bias folded as k=3), LN1 cross-wave stats,
//        normalize+lrelu -> bf16 scatter into frag-major As.
//  GEMM: wave tile 32x64, 16 barrier-free k-steps, A 2-deep LDS, B 3-deep L2.
//  EPI : +b2, LN2, lrelu, layer3 in-reg, shfl + opart reduce.
// R8 delta vs R7: hardware bf16 cvt everywhere (was ~480 VALU inst of manual
// RNE per thread); __launch_bounds__(256,4) (=128 VGPR cap both readings).
// ---------------------------------------------------------------------------
template<bool PREP>
__global__ __launch_bounds__(256, 4) void mlp_main(
  const float* __restrict__ points, const int* __restrict__ cats,
  const float* __restrict__ W1, const float* __restrict__ b1,
  const float* __restrict__ g1, const float* __restrict__ be1,
  const float* __restrict__ W2f, const float* __restrict__ b2,
  const float* __restrict__ g2, const float* __restrict__ be2,
  const float* __restrict__ W3, const float* __restrict__ b3,
  const unsigned short* __restrict__ W2s,
  float* __restrict__ out)
{
  __shared__ unsigned short As[32 * 512];            // 32KB frag-major
  __shared__ __align__(16) float st[32][4][2];       // 1KB cross-wave stats

  const int tid  = (int)threadIdx.x;
  const int lane = tid & 63;
  const int w    = tid >> 6;            // wave 0..3
  const int fr   = lane & 15;
  const int ks4  = lane >> 4;           // k-slot 0..3
  const size_t row0 = (size_t)blockIdx.x * 32;
  const int e = cats[row0 >> 13];

  // ---------------- layer1 via MFMA ----------------
  float al1[2][4], bt1[2][4];
  f32x4 a1[2][8];
  {
    const float* W1e = W1 + (size_t)e * 3 * NH;
    const float* b1e = b1 + (size_t)e * NH;
    // A-frags from points; k-slot 3 carries the bias multiplier 1.0
    short8 apf[2];
    #pragma unroll
    for(int m2 = 0; m2 < 2; m2++){
      const float* pp = points + (row0 + m2 * 16 + fr) * 3;
      float P0 = pp[0], P1 = pp[1], P2 = pp[2];
      union { short8 s; unsigned u[4]; } v;
      v.s = short8{0,0,0,0,0,0,0,0};
      if(ks4 == 0){
        v.u[0] = pkbf(P0, P1);
        v.u[1] = pkbf(P2, 1.0f);
      }
      apf[m2] = v.s;
    }
    #pragma unroll
    for(int n2 = 0; n2 < 8; n2++){
      int col = w * 128 + n2 * 16 + fr;
      union { short8 s; unsigned u[4]; } bw;
      bw.s = short8{0,0,0,0,0,0,0,0};
      bw.u[0] = pkbf(W1e[col], W1e[NH + col]);
      bw.u[1] = pkbf(W1e[2 * NH + col], b1e[col]);
      #pragma unroll
      for(int m2 = 0; m2 < 2; m2++){
        f32x4 z = {0.f, 0.f, 0.f, 0.f};
        a1[m2][n2] = __builtin_amdgcn_mfma_f32_16x16x32_bf16(apf[m2], bw.s, z, 0, 0, 0);
      }
    }
    // LN1 stats: per (m2,r) over this wave's 128 cols, then cross-wave
    #pragma unroll
    for(int m2 = 0; m2 < 2; m2++)
      #pragma unroll
      for(int r = 0; r < 4; r++){
        float s = 0.f, q = 0.f;
        #pragma unroll
        for(int n2 = 0; n2 < 8; n2++){ float x = a1[m2][n2][r]; s += x; q = fmaf(x, x, q); }
        s += __shfl_xor(s, 1); s += __shfl_xor(s, 2); s += __shfl_xor(s, 4); s += __shfl_xor(s, 8);
        q += __shfl_xor(q, 1); q += __shfl_xor(q, 2); q += __shfl_xor(q, 4); q += __shfl_xor(q, 8);
        if(fr == 0){
          st[m2 * 16 + ks4 * 4 + r][w][0] = s;
          st[m2 * 16 + ks4 * 4 + r][w][1] = q;
        }
      }
    __syncthreads();
    #pragma unroll
    for(int m2 = 0; m2 < 2; m2++)
      #pragma unroll
      for(int r = 0; r < 4; r++){
        int row = m2 * 16 + ks4 * 4 + r;
        f32x4 v0 = *(const f32x4*)&st[row][0][0];
        f32x4 v1 = *(const f32x4*)&st[row][2][0];
        float ssum = v0[0] + v0[2] + v1[0] + v1[2];
        float qsum = v0[1] + v0[3] + v1[1] + v1[3];
        float mu = ssum * (1.f / NH);
        float rs = rsqrtf(fmaf(-mu, mu, qsum * (1.f / NH)) + HEPS);
        al1[m2][r] = rs; bt1[m2][r] = -mu * rs;
      }
  }

  // normalize + lrelu -> bf16 scatter into frag-major As
  {
    const float* g1e  = g1  + (size_t)e * NH;
    const float* be1e = be1 + (size_t)e * NH;
    const int laneoff = ((fr >> 3) << 7) + (ks4 << 5) + (fr & 7);
    #pragma unroll
    for(int n2 = 0; n2 < 8; n2++){
      int col = w * 128 + n2 * 16 + fr;
      float gv = g1e[col], bv = be1e[col];
      #pragma unroll
      for(int m2 = 0; m2 < 2; m2++){
        int F = (w * 4 + (n2 >> 1)) * 2 + m2;
        int base = (F << 9) + ((n2 & 1) << 8) + laneoff;
        #pragma unroll
        for(int r = 0; r < 4; r++){
          float x = fmaf(a1[m2][n2][r], al1[m2][r], bt1[m2][r]);
          x = fmaf(x, gv, bv);
          x = fmaxf(x, HSLOPE * x);
          As[base + (r << 3)] = sbf(x);
        }
      }
    }
  }

  // ---------------- B prefetch (L2, prep image) ----------------
  const int wbase = w * 64;
  auto loadB = [&](short8* dst, int t){
    int kc = t >> 1, sub = t & 1;
    #pragma unroll
    for(int n = 0; n < 4; n++){
      if constexpr (PREP){
        const unsigned short* p = W2s + (((size_t)(e * 8 + kc) * 2 + sub) << 13)
                                + (((wbase + n * 16 + fr) << 5) + (ks4 << 3));
        dst[n] = *(const short8*)p;
      } else {
        const float* p = W2f + (((size_t)e * 512 + t * 32 + ks4 * 8) << 8)
                       + (wbase + n * 16 + fr);
        short8 v;
        #pragma unroll
        for(int kk = 0; kk < 8; kk++) v[kk] = (short)sbf(p[(size_t)kk << 8]);
        dst[n] = v;
      }
    }
  };
  short8 bfr[3][4];
  loadB(bfr[0], 0); loadB(bfr[1], 1); loadB(bfr[2], 2);

  __syncthreads();   // As complete

  // ---------------- GEMM: 16 barrier-free k-steps ----------------
  f32x4 acc[2][4];
  #pragma unroll
  for(int m = 0; m < 2; m++)
    #pragma unroll
    for(int n = 0; n < 4; n++){ f32x4 z = {0.f,0.f,0.f,0.f}; acc[m][n] = z; }

  auto loadA = [&](short8* dst, int t){
    dst[0] = *(const short8*)&As[((t * 2 + 0) << 9) + lane * 8];
    dst[1] = *(const short8*)&As[((t * 2 + 1) << 9) + lane * 8];
  };
  short8 afA[2], afB[2];
  loadA(afA, 0);

  #pragma unroll
  for(int t = 0; t < 16; t++){
    short8* af = (t & 1) ? afB : afA;
    if(t < 15) loadA((t & 1) ? afA : afB, t + 1);
    #pragma unroll
    for(int m = 0; m < 2; m++)
      #pragma unroll
      for(int n = 0; n < 4; n++)
        acc[m][n] = __builtin_amdgcn_mfma_f32_16x16x32_bf16(af[m], bfr[t % 3][n], acc[m][n], 0, 0, 0);
    if(t < 13) loadB(bfr[t % 3], t + 3);
  }

  // ---------------- epilogue ----------------
  {
    const float* b2e = b2 + e * 256;
    float bcv[4];
    #pragma unroll
    for(int n = 0; n < 4; n++) bcv[n] = b2e[wbase + n * 16 + fr];
    #pragma unroll
    for(int m = 0; m < 2; m++)
      #pragma unroll
      for(int n = 0; n < 4; n++)
        #pragma unroll
        for(int r = 0; r < 4; r++)
          acc[m][n][r] += bcv[n];

    // LN2 stats
    #pragma unroll
    for(int m = 0; m < 2; m++)
      #pragma unroll
      for(int r = 0; r < 4; r++){
        float s = 0.f, q = 0.f;
        #pragma unroll
        for(int n = 0; n < 4; n++){ float x = acc[m][n][r]; s += x; q = fmaf(x, x, q); }
        s += __shfl_xor(s, 1); s += __shfl_xor(s, 2); s += __shfl_xor(s, 4); s += __shfl_xor(s, 8);
        q += __shfl_xor(q, 1); q += __shfl_xor(q, 2); q += __shfl_xor(q, 4); q += __shfl_xor(q, 8);
        if(fr == 0){
          st[m * 16 + ks4 * 4 + r][w][0] = s;
          st[m * 16 + ks4 * 4 + r][w][1] = q;
        }
      }
    __syncthreads();
    float al2[2][4], bt2[2][4];
    #pragma unroll
    for(int m = 0; m < 2; m++)
      #pragma unroll
      for(int r = 0; r < 4; r++){
        int row = m * 16 + ks4 * 4 + r;
        f32x4 v0 = *(const f32x4*)&st[row][0][0];
        f32x4 v1 = *(const f32x4*)&st[row][2][0];
        float ssum = v0[0] + v0[2] + v1[0] + v1[2];
        float qsum = v0[1] + v0[3] + v1[1] + v1[3];
        float mu = ssum * (1.f / 256.f);
        float rs = rsqrtf(fmaf(-mu, mu, qsum * (1.f / 256.f)) + HEPS);
        al2[m][r] = rs; bt2[m][r] = -mu * rs;
      }

    const float* g2e  = g2  + (size_t)e * 256;
    const float* be2e = be2 + (size_t)e * 256;
    const float* W3e  = W3 + (size_t)e * 256 * 3;
    float o[2][4][3];
    #pragma unroll
    for(int m = 0; m < 2; m++)
      #pragma unroll
      for(int r = 0; r < 4; r++){ o[m][r][0] = 0.f; o[m][r][1] = 0.f; o[m][r][2] = 0.f; }
    #pragma unroll
    for(int n = 0; n < 4; n++){
      int col = wbase + n * 16 + fr;
      float gv = g2e[col], bv = be2e[col];
      float w30 = W3e[col * 3 + 0], w31 = W3e[col * 3 + 1], w32 = W3e[col * 3 + 2];
      #pragma unroll
      for(int m = 0; m < 2; m++)
        #pragma unroll
        for(int r = 0; r < 4; r++){
          float x = fmaf(acc[m][n][r], al2[m][r], bt2[m][r]);
          x = fmaf(x, gv, bv);
          x = fmaxf(x, HSLOPE * x);
          o[m][r][0] = fmaf(x, w30, o[m][r][0]);
          o[m][r][1] = fmaf(x, w31, o[m][r][1]);
          o[m][r][2] = fmaf(x, w32, o[m][r][2]);
        }
    }
    #pragma unroll
    for(int m = 0; m < 2; m++)
      #pragma unroll
      for(int r = 0; r < 4; r++)
        #pragma unroll
        for(int c = 0; c < 3; c++){
          float v = o[m][r][c];
          v += __shfl_xor(v, 1); v += __shfl_xor(v, 2);
          v += __shfl_xor(v, 4); v += __shfl_xor(v, 8);
          o[m][r][c] = v;
        }
    float* opart = (float*)As;   // 32*4*3 floats overlay; As dead after GEMM
    if(fr == 0){
      #pragma unroll
      for(int m = 0; m < 2; m++)
        #pragma unroll
        for(int r = 0; r < 4; r++)
          #pragma unroll
          for(int c = 0; c < 3; c++)
            opart[((m * 16 + ks4 * 4 + r) * 4 + w) * 3 + c] = o[m][r][c];
    }
    __syncthreads();
    if(tid < 96){
      int rr = tid / 3, c = tid - rr * 3;
      float v = b3[e * 3 + c];
      #pragma unroll
      for(int ww = 0; ww < 4; ww++) v += opart[(rr * 4 + ww) * 3 + c];
      out[(row0 + rr) * 3 + c] = v;
    }
  }
}

extern "C" void kernel_launch(void* const* d_in, const int* in_sizes, int n_in,
                              void* d_out, int out_size, void* d_ws, size_t ws_size,
                              hipStream_t stream) {
  const float* points = (const float*)d_in[0];
  const int*   cats   = (const int*)d_in[1];
  const float* W1  = (const float*)d_in[2];
  const float* b1  = (const float*)d_in[3];
  const float* g1  = (const float*)d_in[4];
  const float* be1 = (const float*)d_in[5];
  const float* W2  = (const float*)d_in[6];
  const float* b2  = (const float*)d_in[7];
  const float* g2  = (const float*)d_in[8];
  const float* be2 = (const float*)d_in[9];
  const float* W3  = (const float*)d_in[10];
  const float* b3  = (const float*)d_in[11];
  float* out = (float*)d_out;

  const size_t W2IMG = (size_t)NE * 512 * 256 * 2;   // 2.62 MB bf16 image
  const int grid = NB * NN / 32;                     // 8192 blocks

  if (ws_size >= W2IMG) {
    unsigned short* wsW2 = (unsigned short*)d_ws;
    prep_w2<<<dim3((NE * 512 * 256) / 256), dim3(256), 0, stream>>>(W2, wsW2);
    mlp_main<true><<<dim3(grid), dim3(256), 0, stream>>>(
        points, cats, W1, b1, g1, be1, W2, b2, g2, be2, W3, b3, wsW2, out);
  } else {
    mlp_main<false><<<dim3(grid), dim3(256), 0, stream>>>(
        points, cats, W1, b1, g1, be1, W2, b2, g2, be2, W3, b3, nullptr, out);
  }
}

// Round 9
// 188.387 us; speedup vs baseline: 2.7742x; 1.0729x over previous
//
#include <hip/hip_runtime.h>
#include <hip/hip_bf16.h>
#include <stdint.h>
#include <stddef.h>

#define NB 32
#define NN 8192
#define NH 512
#define NE 10
#define HEPS 1e-5f
#define HSLOPE 0.2f

typedef short short8 __attribute__((ext_vector_type(8)));
typedef float f32x4 __attribute__((ext_vector_type(4)));

static __device__ __forceinline__ unsigned short sbf(float a){
  __hip_bfloat16 t = __float2bfloat16(a);
  return *reinterpret_cast<unsigned short*>(&t);
}
static __device__ __forceinline__ unsigned pkbf(float a, float b){
  float2 f2; f2.x = a; f2.y = b;
  __hip_bfloat162 t = __float22bfloat162_rn(f2);
  return *reinterpret_cast<unsigned*>(&t);
}

// ---------------------------------------------------------------------------
// Prep: W2 [E][512][256] f32 -> bf16 k-major fragment image (proven R2-R8).
// [e][kc(8)][sub(2)][col(256)][kslot(4)][kk(8)]: a wave's W2-frag is one
// coalesced 16B/lane load (64 lanes = contiguous 1KB). Works as A or B
// operand (fragment layouts are symmetric).
// ---------------------------------------------------------------------------
__global__ __launch_bounds__(256) void prep_w2(const float* __restrict__ W2,
                                               unsigned short* __restrict__ ws){
  int idx = blockIdx.x * 256 + threadIdx.x;
  int col = idx & 255;
  int k   = (idx >> 8) & 511;
  int e   = idx >> 17;
  int kc = k >> 6, sub = (k >> 5) & 1, kslot = (k >> 3) & 3, kk = k & 7;
  ws[(((size_t)(e * 8 + kc) * 2 + sub) << 13) + (col << 5) + (kslot << 3) + kk]
      = sbf(W2[idx]);
}

// ---------------------------------------------------------------------------
// Main (R9): SWAPPED operands so point-row = lane&15 in every C-layout ->
// all LN/layer3 reductions are lane-local + 2 shfls (was 4-chain over fr).
//  L1  : a1[mi][ni] = mfma(W1_frag_mi, points_frag_ni): rows of C = W1-cols,
//        cols of C = point-rows. LN1 stats: local sum over mi,r + shfl
//        xor16/32 + cross-wave st (aliased into As[0..511]).
//  GEMM: identical core; acc[mi][ni] = mfma(W2frag_mi, h1frag_ni, acc).
//  EPI : +b2, LN2 (local + 2 shfl + st), lrelu, layer3 with vectorized
//        W3 f32x4 loads, 2-shfl reduce, opart aliased at As[512..1280].
// LDS = exactly 32KB -> 5 blocks/CU (was 33.8KB -> 4).
// ---------------------------------------------------------------------------
template<bool PREP>
__global__ __launch_bounds__(256, 5) void mlp_main(
  const float* __restrict__ points, const int* __restrict__ cats,
  const float* __restrict__ W1, const float* __restrict__ b1,
  const float* __restrict__ g1, const float* __restrict__ be1,
  const float* __restrict__ W2f, const float* __restrict__ b2,
  const float* __restrict__ g2, const float* __restrict__ be2,
  const float* __restrict__ W3, const float* __restrict__ b3,
  const unsigned short* __restrict__ W2s,
  float* __restrict__ out)
{
  __shared__ unsigned short As[32 * 512];     // 32KB exactly; st aliases hw[0..511], opart hw[512..1280]
  float* stf = (float*)As;                    // st[prow][w][2] = stf[prow*8 + w*2 + j]

  const int tid  = (int)threadIdx.x;
  const int lane = tid & 63;
  const int w    = tid >> 6;            // wave 0..3
  const int fr   = lane & 15;
  const int ks4  = lane >> 4;           // k-slot 0..3
  const size_t row0 = (size_t)blockIdx.x * 32;
  const int e = cats[row0 >> 13];
  const int wbase = w * 64;

  // ---------------- layer1 via swapped MFMA ----------------
  f32x4 a1[8][2];                       // [mi: W1-col tile][ni: row half]
  {
    const float* W1e = W1 + (size_t)e * 3 * NH;
    const float* b1e = b1 + (size_t)e * NH;
    short8 apf[2];                      // points as B-operand (n = point-row)
    #pragma unroll
    for(int ni = 0; ni < 2; ni++){
      const float* pp = points + (row0 + ni * 16 + fr) * 3;
      float P0 = pp[0], P1 = pp[1], P2 = pp[2];
      union { short8 s; unsigned u[4]; } v;
      v.s = short8{0,0,0,0,0,0,0,0};
      if(ks4 == 0){ v.u[0] = pkbf(P0, P1); v.u[1] = pkbf(P2, 1.0f); }
      apf[ni] = v.s;
    }
    #pragma unroll
    for(int mi = 0; mi < 8; mi++){
      int col = w * 128 + mi * 16 + fr;      // A-operand m-index = lane&15
      union { short8 s; unsigned u[4]; } bw;
      bw.s = short8{0,0,0,0,0,0,0,0};
      if(ks4 == 0){
        bw.u[0] = pkbf(W1e[col], W1e[NH + col]);
        bw.u[1] = pkbf(W1e[2 * NH + col], b1e[col]);
      }
      #pragma unroll
      for(int ni = 0; ni < 2; ni++){
        f32x4 z = {0.f, 0.f, 0.f, 0.f};
        a1[mi][ni] = __builtin_amdgcn_mfma_f32_16x16x32_bf16(bw.s, apf[ni], z, 0, 0, 0);
      }
    }
  }
  // LN1 stats: per point-row (ni, fr): local over mi,r + shfl over ks4
  float al1[2], bt1[2];
  {
    #pragma unroll
    for(int ni = 0; ni < 2; ni++){
      float s = 0.f, q = 0.f;
      #pragma unroll
      for(int mi = 0; mi < 8; mi++)
        #pragma unroll
        for(int r = 0; r < 4; r++){ float x = a1[mi][ni][r]; s += x; q = fmaf(x, x, q); }
      s += __shfl_xor(s, 16); s += __shfl_xor(s, 32);
      q += __shfl_xor(q, 16); q += __shfl_xor(q, 32);
      if(ks4 == 0){
        float2 sq; sq.x = s; sq.y = q;
        *(float2*)(&stf[(ni * 16 + fr) * 8 + w * 2]) = sq;
      }
    }
    __syncthreads();
    #pragma unroll
    for(int ni = 0; ni < 2; ni++){
      int prow = ni * 16 + fr;
      f32x4 v0 = *(const f32x4*)&stf[prow * 8];
      f32x4 v1 = *(const f32x4*)&stf[prow * 8 + 4];
      float ssum = v0[0] + v0[2] + v1[0] + v1[2];
      float qsum = v0[1] + v0[3] + v1[1] + v1[3];
      float mu = ssum * (1.f / NH);
      float rs = rsqrtf(fmaf(-mu, mu, qsum * (1.f / NH)) + HEPS);
      al1[ni] = rs; bt1[ni] = -mu * rs;
    }
    __syncthreads();   // st fully read before As overwrites it
  }
  // normalize + lrelu -> packed b64 writes into frag-major As
  {
    const float* g1e  = g1  + (size_t)e * NH;
    const float* be1e = be1 + (size_t)e * NH;
    #pragma unroll
    for(int mi = 0; mi < 8; mi++){
      int cb = w * 128 + mi * 16 + ks4 * 4;        // this lane's 4 W1-cols
      f32x4 gg = *(const f32x4*)(g1e + cb);
      f32x4 ee = *(const f32x4*)(be1e + cb);
      #pragma unroll
      for(int ni = 0; ni < 2; ni++){
        float xr[4];
        #pragma unroll
        for(int r = 0; r < 4; r++){
          float x = fmaf(a1[mi][ni][r], al1[ni], bt1[ni]);
          x = fmaf(x, gg[r], ee[r]);
          xr[r] = fmaxf(x, HSLOPE * x);
        }
        uint2 pk; pk.x = pkbf(xr[0], xr[1]); pk.y = pkbf(xr[2], xr[3]);
        int F = (w * 4 + (mi >> 1)) * 2 + ni;
        int addr = (F << 9) + (((mi & 1) * 2 + (ks4 >> 1)) << 7) + fr * 8 + (ks4 & 1) * 4;
        *(uint2*)(&As[addr]) = pk;
      }
    }
  }

  // ---------------- B prefetch: 4 W2-frags (A-operand) per k-step ----------------
  auto loadB = [&](short8* dst, int t){
    int kc = t >> 1, sub = t & 1;
    #pragma unroll
    for(int mi = 0; mi < 4; mi++){
      if constexpr (PREP){
        const unsigned short* p = W2s + (((size_t)(e * 8 + kc) * 2 + sub) << 13)
                                + (((wbase + mi * 16 + fr) << 5) + (ks4 << 3));
        dst[mi] = *(const short8*)p;
      } else {
        const float* p = W2f + (((size_t)e * 512 + t * 32 + ks4 * 8) << 8)
                       + (wbase + mi * 16 + fr);
        short8 v;
        #pragma unroll
        for(int kk = 0; kk < 8; kk++) v[kk] = (short)sbf(p[(size_t)kk << 8]);
        dst[mi] = v;
      }
    }
  };
  short8 bfr[3][4];
  loadB(bfr[0], 0); loadB(bfr[1], 1); loadB(bfr[2], 2);

  __syncthreads();   // As complete

  // ---------------- GEMM: 16 barrier-free k-steps (swapped operands) ----------------
  f32x4 acc[4][2];   // [mi: W2-col tile][ni: row half]
  #pragma unroll
  for(int m = 0; m < 4; m++)
    #pragma unroll
    for(int n = 0; n < 2; n++){ f32x4 z = {0.f,0.f,0.f,0.f}; acc[m][n] = z; }

  auto loadA = [&](short8* dst, int t){
    dst[0] = *(const short8*)&As[((t * 2 + 0) << 9) + lane * 8];
    dst[1] = *(const short8*)&As[((t * 2 + 1) << 9) + lane * 8];
  };
  short8 afA[2], afB[2];
  loadA(afA, 0);

  #pragma unroll
  for(int t = 0; t < 16; t++){
    short8* af = (t & 1) ? afB : afA;
    if(t < 15) loadA((t & 1) ? afA : afB, t + 1);
    #pragma unroll
    for(int m = 0; m < 4; m++)
      #pragma unroll
      for(int n = 0; n < 2; n++)
        acc[m][n] = __builtin_amdgcn_mfma_f32_16x16x32_bf16(bfr[t % 3][m], af[n], acc[m][n], 0, 0, 0);
    if(t < 13) loadB(bfr[t % 3], t + 3);
  }

  __syncthreads();   // GEMM done before st2 overwrites As-alias

  // ---------------- epilogue: +b2, LN2, lrelu, layer3 ----------------
  {
    const float* b2e = b2 + (size_t)e * 256;
    #pragma unroll
    for(int mi = 0; mi < 4; mi++){
      int cb = wbase + mi * 16 + ks4 * 4;
      f32x4 bb = *(const f32x4*)(b2e + cb);
      #pragma unroll
      for(int ni = 0; ni < 2; ni++)
        #pragma unroll
        for(int r = 0; r < 4; r++)
          acc[mi][ni][r] += bb[r];
    }
    // LN2 stats: local over mi,r + shfl over ks4 + cross-wave st
    float al2[2], bt2[2];
    #pragma unroll
    for(int ni = 0; ni < 2; ni++){
      float s = 0.f, q = 0.f;
      #pragma unroll
      for(int mi = 0; mi < 4; mi++)
        #pragma unroll
        for(int r = 0; r < 4; r++){ float x = acc[mi][ni][r]; s += x; q = fmaf(x, x, q); }
      s += __shfl_xor(s, 16); s += __shfl_xor(s, 32);
      q += __shfl_xor(q, 16); q += __shfl_xor(q, 32);
      if(ks4 == 0){
        float2 sq; sq.x = s; sq.y = q;
        *(float2*)(&stf[(ni * 16 + fr) * 8 + w * 2]) = sq;
      }
    }
    __syncthreads();
    #pragma unroll
    for(int ni = 0; ni < 2; ni++){
      int prow = ni * 16 + fr;
      f32x4 v0 = *(const f32x4*)&stf[prow * 8];
      f32x4 v1 = *(const f32x4*)&stf[prow * 8 + 4];
      float ssum = v0[0] + v0[2] + v1[0] + v1[2];
      float qsum = v0[1] + v0[3] + v1[1] + v1[3];
      float mu = ssum * (1.f / 256.f);
      float rs = rsqrtf(fmaf(-mu, mu, qsum * (1.f / 256.f)) + HEPS);
      al2[ni] = rs; bt2[ni] = -mu * rs;
    }
    // normalize + lrelu + layer3 (vectorized W3)
    const float* g2e  = g2  + (size_t)e * 256;
    const float* be2e = be2 + (size_t)e * 256;
    const float* W3e  = W3 + (size_t)e * 256 * 3;
    float o[2][3];
    o[0][0]=0.f;o[0][1]=0.f;o[0][2]=0.f;o[1][0]=0.f;o[1][1]=0.f;o[1][2]=0.f;
    #pragma unroll
    for(int mi = 0; mi < 4; mi++){
      int cb = wbase + mi * 16 + ks4 * 4;
      f32x4 gg = *(const f32x4*)(g2e + cb);
      f32x4 ee = *(const f32x4*)(be2e + cb);
      f32x4 w3v0 = *(const f32x4*)(W3e + cb * 3);
      f32x4 w3v1 = *(const f32x4*)(W3e + cb * 3 + 4);
      f32x4 w3v2 = *(const f32x4*)(W3e + cb * 3 + 8);
      float w3f[12];
      *(f32x4*)(w3f) = w3v0; *(f32x4*)(w3f + 4) = w3v1; *(f32x4*)(w3f + 8) = w3v2;
      #pragma unroll
      for(int ni = 0; ni < 2; ni++)
        #pragma unroll
        for(int r = 0; r < 4; r++){
          float x = fmaf(acc[mi][ni][r], al2[ni], bt2[ni]);
          x = fmaf(x, gg[r], ee[r]);
          x = fmaxf(x, HSLOPE * x);
          o[ni][0] = fmaf(x, w3f[r * 3 + 0], o[ni][0]);
          o[ni][1] = fmaf(x, w3f[r * 3 + 1], o[ni][1]);
          o[ni][2] = fmaf(x, w3f[r * 3 + 2], o[ni][2]);
        }
    }
    #pragma unroll
    for(int ni = 0; ni < 2; ni++)
      #pragma unroll
      for(int c = 0; c < 3; c++){
        float v = o[ni][c];
        v += __shfl_xor(v, 16); v += __shfl_xor(v, 32);
        o[ni][c] = v;
      }
    float* opart = stf + 256;   // [32][4][3] floats at As hw[512..1280]
    if(ks4 == 0){
      #pragma unroll
      for(int ni = 0; ni < 2; ni++)
        #pragma unroll
        for(int c = 0; c < 3; c++)
          opart[(ni * 16 + fr) * 12 + w * 3 + c] = o[ni][c];
    }
    __syncthreads();
    if(tid < 96){
      int rr = tid / 3, c = tid - rr * 3;
      float v = b3[e * 3 + c];
      #pragma unroll
      for(int ww = 0; ww < 4; ww++) v += opart[rr * 12 + ww * 3 + c];
      out[(row0 + rr) * 3 + c] = v;
    }
  }
}

extern "C" void kernel_launch(void* const* d_in, const int* in_sizes, int n_in,
                              void* d_out, int out_size, void* d_ws, size_t ws_size,
                              hipStream_t stream) {
  const float* points = (const float*)d_in[0];
  const int*   cats   = (const int*)d_in[1];
  const float* W1  = (const float*)d_in[2];
  const float* b1  = (const float*)d_in[3];
  const float* g1  = (const float*)d_in[4];
  const float* be1 = (const float*)d_in[5];
  const float* W2  = (const float*)d_in[6];
  const float* b2  = (const float*)d_in[7];
  const float* g2  = (const float*)d_in[8];
  const float* be2 = (const float*)d_in[9];
  const float* W3  = (const float*)d_in[10];
  const float* b3  = (const float*)d_in[11];
  float* out = (float*)d_out;

  const size_t W2IMG = (size_t)NE * 512 * 256 * 2;   // 2.62 MB bf16 image
  const int grid = NB * NN / 32;                     // 8192 blocks

  if (ws_size >= W2IMG) {
    unsigned short* wsW2 = (unsigned short*)d_ws;
    prep_w2<<<dim3((NE * 512 * 256) / 256), dim3(256), 0, stream>>>(W2, wsW2);
    mlp_main<true><<<dim3(grid), dim3(256), 0, stream>>>(
        points, cats, W1, b1, g1, be1, W2, b2, g2, be2, W3, b3, wsW2, out);
  } else {
    mlp_main<false><<<dim3(grid), dim3(256), 0, stream>>>(
        points, cats, W1, b1, g1, be1, W2, b2, g2, be2, W3, b3, nullptr, out);
  }
}

// Round 10
// 154.408 us; speedup vs baseline: 3.3848x; 1.2201x over previous
//
#include <hip/hip_runtime.h>
#include <hip/hip_bf16.h>
#include <stdint.h>
#include <stddef.h>

#define NB 32
#define NN 8192
#define NH 512
#define NE 10
#define HEPS 1e-5f
#define HSLOPE 0.2f

typedef short short8 __attribute__((ext_vector_type(8)));
typedef float f32x4 __attribute__((ext_vector_type(4)));
typedef float f32x16 __attribute__((ext_vector_type(16)));

static __device__ __forceinline__ unsigned short sbf(float a){
  __hip_bfloat16 t = __float2bfloat16(a);
  return *reinterpret_cast<unsigned short*>(&t);
}
static __device__ __forceinline__ unsigned pkbf(float a, float b){
  float2 f2; f2.x = a; f2.y = b;
  __hip_bfloat162 t = __float22bfloat162_rn(f2);
  return *reinterpret_cast<unsigned*>(&t);
}

// ---------------------------------------------------------------------------
// Prep: W2 [E][512][256] f32 -> bf16 image for 32x32x16 fragments.
// [e][t(32)][col(256)][kh(2)][kk(8)]: a wave's 32-col B-frag at k-step t is
// one coalesced 16B/lane load (64 lanes = contiguous 1KB).
// ---------------------------------------------------------------------------
__global__ __launch_bounds__(256) void prep_w2(const float* __restrict__ W2,
                                               unsigned short* __restrict__ ws){
  int idx = blockIdx.x * 256 + threadIdx.x;
  int col = idx & 255;
  int k   = (idx >> 8) & 511;
  int e   = idx >> 17;
  int t = k >> 4, kh = (k >> 3) & 1, kk = k & 7;
  ws[(((size_t)(e * 32 + t)) << 12) + (col << 4) + (kh << 3) + kk] = sbf(W2[idx]);
}

// ---------------------------------------------------------------------------
// Main (R10): all-32x32x16 MFMA pipeline. Block = 32 rows, 4 waves; wave =
// 32 rows x 64 cols (2 m-frags). C layout: col=lane&31=point-row (lane-local
// LN), row=(r&3)+8*(r>>2)+4*(lane>>5) = feature col.
//  L1  : 4 MFMA (W1 frag x points frag, bias at k=3), LN1 = local sum +
//        1 shfl + cross-wave stf; normalize+lrelu -> packed uint2 into
//        frag-major As (conflict-free by octet audit).
//  GEMM: 32 k-steps x {1 ds_read_b128 A, 2x16B B-load, 2 MFMA}, 3-deep B
//        prefetch, barrier-free.
//  EPI : +b2, LN2 (local + 1 shfl + stf), lrelu, layer3 f32x4-vectorized,
//        1-shfl reduce, opart (aliased) cross-wave.
// LDS 32KB exactly; stats/opart alias As. 6 barriers.
// ---------------------------------------------------------------------------
template<bool PREP>
__global__ __launch_bounds__(256, 4) void mlp_main(
  const float* __restrict__ points, const int* __restrict__ cats,
  const float* __restrict__ W1, const float* __restrict__ b1,
  const float* __restrict__ g1, const float* __restrict__ be1,
  const float* __restrict__ W2f, const float* __restrict__ b2,
  const float* __restrict__ g2, const float* __restrict__ be2,
  const float* __restrict__ W3, const float* __restrict__ b3,
  const unsigned short* __restrict__ W2s,
  float* __restrict__ out)
{
  __shared__ unsigned short As[32 * 512];   // 32KB; frag t at [t*512]: [kh(2)][pr(32)][kk(8)]
  float* stf = (float*)As;                  // stats alias hw[0..512); opart hw[512..1280)

  const int tid  = (int)threadIdx.x;
  const int lane = tid & 63;
  const int w    = tid >> 6;            // wave 0..3
  const int pr   = lane & 31;           // point-row (C col)
  const int kh   = lane >> 5;           // k-half
  const size_t row0 = (size_t)blockIdx.x * 32;
  const int e = cats[row0 >> 13];
  const int wbase = w * 64;

  // ---------------- layer1 via 32x32x16 MFMA ----------------
  f32x16 a1[4];
  float al1, bt1;
  {
    const float* W1e = W1 + (size_t)e * 3 * NH;
    const float* b1e = b1 + (size_t)e * NH;
    short8 apf;                         // points as B-operand (n = point-row)
    {
      const float* pp = points + (row0 + pr) * 3;
      union { short8 s; unsigned u[4]; } v;
      v.s = short8{0,0,0,0,0,0,0,0};
      if(kh == 0){ v.u[0] = pkbf(pp[0], pp[1]); v.u[1] = pkbf(pp[2], 1.0f); }
      apf = v.s;
    }
    #pragma unroll
    for(int mi = 0; mi < 4; mi++){
      int col = w * 128 + mi * 32 + pr;      // A-operand m = lane&31
      union { short8 s; unsigned u[4]; } bw;
      bw.s = short8{0,0,0,0,0,0,0,0};
      if(kh == 0){
        bw.u[0] = pkbf(W1e[col], W1e[NH + col]);
        bw.u[1] = pkbf(W1e[2 * NH + col], b1e[col]);
      }
      f32x16 z = {0.f,0.f,0.f,0.f,0.f,0.f,0.f,0.f,0.f,0.f,0.f,0.f,0.f,0.f,0.f,0.f};
      a1[mi] = __builtin_amdgcn_mfma_f32_32x32x16_bf16(bw.s, apf, z, 0, 0, 0);
    }
    // LN1 stats: all of lane's values belong to point-row pr
    float s = 0.f, q = 0.f;
    #pragma unroll
    for(int mi = 0; mi < 4; mi++)
      #pragma unroll
      for(int r = 0; r < 16; r++){ float x = a1[mi][r]; s += x; q = fmaf(x, x, q); }
    s += __shfl_xor(s, 32); q += __shfl_xor(q, 32);
    if(kh == 0){
      float2 sq; sq.x = s; sq.y = q;
      *(float2*)(&stf[pr * 8 + w * 2]) = sq;
    }
    __syncthreads();
    {
      f32x4 v0 = *(const f32x4*)&stf[pr * 8];
      f32x4 v1 = *(const f32x4*)&stf[pr * 8 + 4];
      float ssum = v0[0] + v0[2] + v1[0] + v1[2];
      float qsum = v0[1] + v0[3] + v1[1] + v1[3];
      float mu = ssum * (1.f / NH);
      float rs = rsqrtf(fmaf(-mu, mu, qsum * (1.f / NH)) + HEPS);
      al1 = rs; bt1 = -mu * rs;
    }
    __syncthreads();   // stf fully read before As overwrite
  }
  // normalize + lrelu -> packed uint2 into frag-major As
  {
    const float* g1e  = g1  + (size_t)e * NH;
    const float* be1e = be1 + (size_t)e * NH;
    #pragma unroll
    for(int mi = 0; mi < 4; mi++){
      #pragma unroll
      for(int a = 0; a < 4; a++){
        int cb = w * 128 + mi * 32 + a * 8 + kh * 4;   // 4 feature cols
        f32x4 gg = *(const f32x4*)(g1e + cb);
        f32x4 ee = *(const f32x4*)(be1e + cb);
        float xr[4];
        #pragma unroll
        for(int j = 0; j < 4; j++){
          float x = fmaf(a1[mi][a * 4 + j], al1, bt1);
          x = fmaf(x, gg[j], ee[j]);
          xr[j] = fmaxf(x, HSLOPE * x);
        }
        uint2 pk; pk.x = pkbf(xr[0], xr[1]); pk.y = pkbf(xr[2], xr[3]);
        int addr = ((w * 8 + mi * 2 + (a >> 1)) << 9) + ((a & 1) << 8) + pr * 8 + kh * 4;
        *(uint2*)(&As[addr]) = pk;
      }
    }
  }

  // ---------------- B prefetch (W2 as A-operand) ----------------
  auto loadB = [&](short8* dst, int t){
    #pragma unroll
    for(int mi = 0; mi < 2; mi++){
      if constexpr (PREP){
        const unsigned short* p = W2s + (((size_t)(e * 32 + t)) << 12)
                                + ((wbase + mi * 32 + pr) << 4) + (kh << 3);
        dst[mi] = *(const short8*)p;
      } else {
        const float* p = W2f + (((size_t)e * 512 + t * 16 + kh * 8) << 8)
                       + (wbase + mi * 32 + pr);
        short8 v;
        #pragma unroll
        for(int kk = 0; kk < 8; kk++) v[kk] = (short)sbf(p[(size_t)kk << 8]);
        dst[mi] = v;
      }
    }
  };
  short8 bfr[3][2];
  loadB(bfr[0], 0); loadB(bfr[1], 1); loadB(bfr[2], 2);

  __syncthreads();   // As complete

  // ---------------- GEMM: 32 barrier-free k-steps ----------------
  f32x16 acc[2];
  {
    f32x16 z = {0.f,0.f,0.f,0.f,0.f,0.f,0.f,0.f,0.f,0.f,0.f,0.f,0.f,0.f,0.f,0.f};
    acc[0] = z; acc[1] = z;
  }
  const int aoff = (kh << 8) + pr * 8;
  short8 afA, afB;
  afA = *(const short8*)&As[aoff];

  #pragma unroll
  for(int t = 0; t < 32; t++){
    short8 af = (t & 1) ? afB : afA;
    if(t < 31){
      short8 nx = *(const short8*)&As[((t + 1) << 9) + aoff];
      if(t & 1) afA = nx; else afB = nx;
    }
    acc[0] = __builtin_amdgcn_mfma_f32_32x32x16_bf16(bfr[t % 3][0], af, acc[0], 0, 0, 0);
    acc[1] = __builtin_amdgcn_mfma_f32_32x32x16_bf16(bfr[t % 3][1], af, acc[1], 0, 0, 0);
    if(t < 29) loadB(bfr[t % 3], t + 3);
  }

  __syncthreads();   // GEMM As reads done before stf2 aliases

  // ---------------- epilogue: +b2, LN2, lrelu, layer3 ----------------
  {
    const float* b2e = b2 + (size_t)e * 256;
    #pragma unroll
    for(int mi = 0; mi < 2; mi++)
      #pragma unroll
      for(int a = 0; a < 4; a++){
        int cb = wbase + mi * 32 + a * 8 + kh * 4;
        f32x4 bb = *(const f32x4*)(b2e + cb);
        #pragma unroll
        for(int j = 0; j < 4; j++) acc[mi][a * 4 + j] += bb[j];
      }
    // LN2 stats
    float al2, bt2;
    {
      float s = 0.f, q = 0.f;
      #pragma unroll
      for(int mi = 0; mi < 2; mi++)
        #pragma unroll
        for(int r = 0; r < 16; r++){ float x = acc[mi][r]; s += x; q = fmaf(x, x, q); }
      s += __shfl_xor(s, 32); q += __shfl_xor(q, 32);
      if(kh == 0){
        float2 sq; sq.x = s; sq.y = q;
        *(float2*)(&stf[pr * 8 + w * 2]) = sq;
      }
      __syncthreads();
      f32x4 v0 = *(const f32x4*)&stf[pr * 8];
      f32x4 v1 = *(const f32x4*)&stf[pr * 8 + 4];
      float ssum = v0[0] + v0[2] + v1[0] + v1[2];
      float qsum = v0[1] + v0[3] + v1[1] + v1[3];
      float mu = ssum * (1.f / 256.f);
      float rs = rsqrtf(fmaf(-mu, mu, qsum * (1.f / 256.f)) + HEPS);
      al2 = rs; bt2 = -mu * rs;
    }
    // normalize + lrelu + layer3 (vectorized)
    const float* g2e  = g2  + (size_t)e * 256;
    const float* be2e = be2 + (size_t)e * 256;
    const float* W3e  = W3 + (size_t)e * 256 * 3;
    float o0 = 0.f, o1 = 0.f, o2 = 0.f;
    #pragma unroll
    for(int mi = 0; mi < 2; mi++)
      #pragma unroll
      for(int a = 0; a < 4; a++){
        int cb = wbase + mi * 32 + a * 8 + kh * 4;
        f32x4 gg = *(const f32x4*)(g2e + cb);
        f32x4 ee = *(const f32x4*)(be2e + cb);
        float w3f[12];
        *(f32x4*)(w3f)     = *(const f32x4*)(W3e + cb * 3);
        *(f32x4*)(w3f + 4) = *(const f32x4*)(W3e + cb * 3 + 4);
        *(f32x4*)(w3f + 8) = *(const f32x4*)(W3e + cb * 3 + 8);
        #pragma unroll
        for(int j = 0; j < 4; j++){
          float x = fmaf(acc[mi][a * 4 + j], al2, bt2);
          x = fmaf(x, gg[j], ee[j]);
          x = fmaxf(x, HSLOPE * x);
          o0 = fmaf(x, w3f[j * 3 + 0], o0);
          o1 = fmaf(x, w3f[j * 3 + 1], o1);
          o2 = fmaf(x, w3f[j * 3 + 2], o2);
        }
      }
    o0 += __shfl_xor(o0, 32); o1 += __shfl_xor(o1, 32); o2 += __shfl_xor(o2, 32);
    float* opart = stf + 256;   // [32][4][3] at hw[512..1280) — disjoint from stf[0..256)
    if(kh == 0){
      opart[pr * 12 + w * 3 + 0] = o0;
      opart[pr * 12 + w * 3 + 1] = o1;
      opart[pr * 12 + w * 3 + 2] = o2;
    }
    __syncthreads();
    if(tid < 96){
      int rr = tid / 3, c = tid - rr * 3;
      float v = b3[e * 3 + c];
      #pragma unroll
      for(int ww = 0; ww < 4; ww++) v += opart[rr * 12 + ww * 3 + c];
      out[(row0 + rr) * 3 + c] = v;
    }
  }
}

extern "C" void kernel_launch(void* const* d_in, const int* in_sizes, int n_in,
                              void* d_out, int out_size, void* d_ws, size_t ws_size,
                              hipStream_t stream) {
  const float* points = (const float*)d_in[0];
  const int*   cats   = (const int*)d_in[1];
  const float* W1  = (const float*)d_in[2];
  const float* b1  = (const float*)d_in[3];
  const float* g1  = (const float*)d_in[4];
  const float* be1 = (const float*)d_in[5];
  const float* W2  = (const float*)d_in[6];
  const float* b2  = (const float*)d_in[7];
  const float* g2  = (const float*)d_in[8];
  const float* be2 = (const float*)d_in[9];
  const float* W3  = (const float*)d_in[10];
  const float* b3  = (const float*)d_in[11];
  float* out = (float*)d_out;

  const size_t W2IMG = (size_t)NE * 512 * 256 * 2;   // 2.62 MB bf16 image
  const int grid = NB * NN / 32;                     // 8192 blocks

  if (ws_size >= W2IMG) {
    unsigned short* wsW2 = (unsigned short*)d_ws;
    prep_w2<<<dim3((NE * 512 * 256) / 256), dim3(256), 0, stream>>>(W2, wsW2);
    mlp_main<true><<<dim3(grid), dim3(256), 0, stream>>>(
        points, cats, W1, b1, g1, be1, W2, b2, g2, be2, W3, b3, wsW2, out);
  } else {
    mlp_main<false><<<dim3(grid), dim3(256), 0, stream>>>(
        points, cats, W1, b1, g1, be1, W2, b2, g2, be2, W3, b3, nullptr, out);
  }
}